// Round 1
// baseline (1704.270 us; speedup 1.0000x reference)
//
#include <hip/hip_runtime.h>
#include <cstdint>

// ---------------------------------------------------------------------------
// EETransformerEncoder on MI355X (gfx950).
// Residual stream x kept fp32; GEMM operands bf16 (MFMA 16x16x32), fp32 acc.
// pos_k[t,s] == pe_k[t-s+1000] (no clipping at T=512), so the per-layer
// norm_k is a 2000x64 table; rel-pos bias is computed in-attention via a
// small MFMA GEMM against gathered table rows.
// ---------------------------------------------------------------------------

typedef __bf16 bf16_t;
typedef bf16_t bf16x4 __attribute__((ext_vector_type(4)));
typedef bf16_t bf16x8 __attribute__((ext_vector_type(8)));
typedef float  f32x4  __attribute__((ext_vector_type(4)));

#define B_    8
#define T_    512
#define IDIM  1799
#define KPAD  1824        // 57*32
#define D_    256
#define H_    4
#define DK    64
#define FF_   2048
#define L_    16
#define NROW  4096        // B_*T_
#define PKROWS 2000       // 2*MAXLEN

__device__ __forceinline__ f32x4 mfma16(bf16x8 a, bf16x8 b, f32x4 c) {
  return __builtin_amdgcn_mfma_f32_16x16x32_bf16(a, b, c, 0, 0, 0);
}

// async global->LDS, 16B per lane. LDS dest must be wave-uniform base; HW adds lane*16.
__device__ __forceinline__ void async_cp16(const void* g, void* l) {
  __builtin_amdgcn_global_load_lds(
      (__attribute__((address_space(1))) void*)(g),
      (__attribute__((address_space(3))) void*)(l), 16, 0, 0);
}

// ---------------------------------------------------------------------------
// conversions / packing
// ---------------------------------------------------------------------------
__global__ __launch_bounds__(256) void cvt_f32_bf16(const float* __restrict__ s,
                                                    bf16_t* __restrict__ d, int n) {
  int i = blockIdx.x * 256 + threadIdx.x;
  int stride = gridDim.x * 256;
  for (; i < n; i += stride) d[i] = (bf16_t)s[i];
}

// one block per row; pads K to kdst with zeros
__global__ __launch_bounds__(256) void cvt_pad_row(const float* __restrict__ s,
                                                   bf16_t* __restrict__ d,
                                                   int ksrc, int kdst) {
  const int r = blockIdx.x;
  const float* sr = s + (size_t)r * ksrc;
  bf16_t* dr = d + (size_t)r * kdst;
  for (int k = threadIdx.x; k < kdst; k += 256)
    dr[k] = (k < ksrc) ? (bf16_t)sr[k] : (bf16_t)0.f;
}

// pack Wq|Wk|Wv -> [L][768][256] bf16
__global__ __launch_bounds__(256) void pack_qkvw(const float* __restrict__ wq,
                                                 const float* __restrict__ wk,
                                                 const float* __restrict__ wv,
                                                 bf16_t* __restrict__ dst) {
  const int per_l = 768 * 256;
  int i = blockIdx.x * 256 + threadIdx.x;
  int stride = gridDim.x * 256;
  for (; i < L_ * per_l; i += stride) {
    int l = i / per_l, r = i - l * per_l;
    int n = r >> 8, c = r & 255;
    int sel = n >> 8, nn = n & 255;
    const float* w = (sel == 0) ? wq : (sel == 1) ? wk : wv;
    dst[i] = (bf16_t)w[((size_t)l * 256 + nn) * 256 + c];
  }
}

__global__ __launch_bounds__(256) void pack_qkvb(const float* __restrict__ bq,
                                                 const float* __restrict__ bk,
                                                 const float* __restrict__ bv,
                                                 float* __restrict__ dst) {
  int i = blockIdx.x * 256 + threadIdx.x;
  if (i >= L_ * 768) return;
  int l = i / 768, n = i - l * 768;
  int sel = n >> 8, nn = n & 255;
  const float* b = (sel == 0) ? bq : (sel == 1) ? bk : bv;
  dst[i] = b[l * 256 + nn];
}

// per-layer LN of pe_k rows: out[l][r][d], one wave per (l,r)
__global__ __launch_bounds__(256) void pkn_ln(const float* __restrict__ pe_k,
                                              const float* __restrict__ lnk_g,
                                              const float* __restrict__ lnk_b,
                                              bf16_t* __restrict__ out) {
  const int idx = blockIdx.x * 4 + (threadIdx.x >> 6);
  if (idx >= L_ * PKROWS) return;
  const int lane = threadIdx.x & 63;
  const int l = idx / PKROWS, r = idx - l * PKROWS;
  float v = pe_k[(size_t)r * DK + lane];
  float s = v;
#pragma unroll
  for (int o = 32; o; o >>= 1) s += __shfl_xor(s, o);
  const float mean = s * (1.f / DK);
  const float dx = v - mean;
  float q = dx * dx;
#pragma unroll
  for (int o = 32; o; o >>= 1) q += __shfl_xor(q, o);
  const float rs = rsqrtf(q * (1.f / DK) + 1e-12f);
  out[((size_t)l * PKROWS + r) * DK + lane] =
      (bf16_t)(dx * rs * lnk_g[l * DK + lane] + lnk_b[l * DK + lane]);
}

// ---------------------------------------------------------------------------
// LayerNorm over rows of 256 (one wave per row)
// ---------------------------------------------------------------------------
template <bool BF16OUT, bool RELU>
__global__ __launch_bounds__(256) void ln_rows(const float* __restrict__ src,
                                               const float* __restrict__ g,
                                               const float* __restrict__ b,
                                               void* __restrict__ dst) {
  const int row = blockIdx.x * 4 + (threadIdx.x >> 6);
  const int lane = threadIdx.x & 63;
  const float4 v = ((const float4*)(src + (size_t)row * D_))[lane];
  float s = v.x + v.y + v.z + v.w;
#pragma unroll
  for (int o = 32; o; o >>= 1) s += __shfl_xor(s, o);
  const float mean = s * (1.f / D_);
  const float d0 = v.x - mean, d1 = v.y - mean, d2 = v.z - mean, d3 = v.w - mean;
  float q = d0 * d0 + d1 * d1 + d2 * d2 + d3 * d3;
#pragma unroll
  for (int o = 32; o; o >>= 1) q += __shfl_xor(q, o);
  const float rs = rsqrtf(q * (1.f / D_) + 1e-12f);
  const float4 gg = ((const float4*)g)[lane];
  const float4 bb = ((const float4*)b)[lane];
  float o0 = d0 * rs * gg.x + bb.x;
  float o1 = d1 * rs * gg.y + bb.y;
  float o2 = d2 * rs * gg.z + bb.z;
  float o3 = d3 * rs * gg.w + bb.w;
  if (RELU) {
    o0 = fmaxf(o0, 0.f); o1 = fmaxf(o1, 0.f);
    o2 = fmaxf(o2, 0.f); o3 = fmaxf(o3, 0.f);
  }
  if (BF16OUT) {
    bf16x4 o4 = {(bf16_t)o0, (bf16_t)o1, (bf16_t)o2, (bf16_t)o3};
    ((bf16x4*)((bf16_t*)dst + (size_t)row * D_))[lane] = o4;
  } else {
    ((float4*)((float*)dst + (size_t)row * D_))[lane] = make_float4(o0, o1, o2, o3);
  }
}

// ---------------------------------------------------------------------------
// bf16 NT GEMM: C[M,N] = A[M,K] * B[N,K]^T (+bias / relu / residual)
// BK=32, global_load_lds(16B) staging, XOR-swizzled LDS (2-way max on reads).
// EP: 0 = f32 bias; 1 = bf16 bias; 2 = bf16 bias+relu; 3 = f32 bias+resid
// ---------------------------------------------------------------------------
template <int BM, int BN, int EP>
__global__ __launch_bounds__(256, 2) void gemm_bf16(
    const bf16_t* __restrict__ A, int lda, const bf16_t* __restrict__ B, int ldb,
    const float* __restrict__ bias, void* __restrict__ Cout, int ldc,
    const float* __restrict__ resid, int K) {
  constexpr int HM = BM / 2, HN = BN / 2;
  constexpr int FM = HM / 16, FN = HN / 16;
  constexpr int CA = (BM * 4) / 256, CB = (BN * 4) / 256;
  __shared__ bf16_t lsA[BM * 32];
  __shared__ bf16_t lsB[BN * 32];
  const int tid = threadIdx.x;
  const int w = tid >> 6, lane = tid & 63;
  const int wm = w >> 1, wn = w & 1;
  const int lanelo = lane & 15, quad = lane >> 4;
  const int wbase = tid & ~63;
  const int m0 = blockIdx.x * BM, n0 = blockIdx.y * BN;
  f32x4 acc[FM][FN] = {};

  for (int kt = 0; kt < K; kt += 32) {
    __syncthreads();
#pragma unroll
    for (int rr = 0; rr < CA; ++rr) {
      int chunk = rr * 256 + tid;
      int r = chunk >> 2, qs = chunk & 3;
      int qg = qs ^ ((r >> 1) & 3);
      async_cp16(A + (size_t)(m0 + r) * lda + kt + qg * 8,
                 lsA + (size_t)(rr * 256 + wbase) * 8);
    }
#pragma unroll
    for (int rr = 0; rr < CB; ++rr) {
      int chunk = rr * 256 + tid;
      int r = chunk >> 2, qs = chunk & 3;
      int qg = qs ^ ((r >> 1) & 3);
      async_cp16(B + (size_t)(n0 + r) * ldb + kt + qg * 8,
                 lsB + (size_t)(rr * 256 + wbase) * 8);
    }
    __syncthreads();
    bf16x8 af[FM], bfv[FN];
#pragma unroll
    for (int i = 0; i < FM; ++i) {
      int r = wm * HM + i * 16 + lanelo;
      af[i] = *(const bf16x8*)(lsA + (size_t)(r * 4 + (quad ^ ((r >> 1) & 3))) * 8);
    }
#pragma unroll
    for (int j = 0; j < FN; ++j) {
      int r = wn * HN + j * 16 + lanelo;
      bfv[j] = *(const bf16x8*)(lsB + (size_t)(r * 4 + (quad ^ ((r >> 1) & 3))) * 8);
    }
#pragma unroll
    for (int i = 0; i < FM; ++i)
#pragma unroll
      for (int j = 0; j < FN; ++j) acc[i][j] = mfma16(af[i], bfv[j], acc[i][j]);
  }

#pragma unroll
  for (int i = 0; i < FM; ++i) {
#pragma unroll
    for (int j = 0; j < FN; ++j) {
#pragma unroll
      for (int reg = 0; reg < 4; ++reg) {
        const int m = m0 + wm * HM + i * 16 + quad * 4 + reg;
        const int n = n0 + wn * HN + j * 16 + lanelo;
        const size_t idx = (size_t)m * ldc + n;
        float v = acc[i][j][reg] + bias[n];
        if constexpr (EP == 0) {
          ((float*)Cout)[idx] = v;
        } else if constexpr (EP == 1) {
          ((bf16_t*)Cout)[idx] = (bf16_t)v;
        } else if constexpr (EP == 2) {
          ((bf16_t*)Cout)[idx] = (bf16_t)fmaxf(v, 0.f);
        } else {
          ((float*)Cout)[idx] = v + resid[idx];
        }
      }
    }
  }
}

// ---------------------------------------------------------------------------
// Fused attention: per (b,h, 64-row q tile), flash-style over s tiles of 64.
// scores = (q.k^T + q.pkn[t-s+1000]) * 1/8, mask, online softmax, O = P.V.
// qkv rows: [4096][768] bf16 (q|k|v each 256 wide), out: [4096][256] bf16.
// ---------------------------------------------------------------------------
__global__ __launch_bounds__(256, 2) void attn_fused(
    const bf16_t* __restrict__ qkv, const bf16_t* __restrict__ pkn,
    const int* __restrict__ masks, bf16_t* __restrict__ out) {
  __shared__ bf16_t ls_q[64 * 72];
  __shared__ bf16_t ls_k[64 * 72];
  __shared__ bf16_t ls_vt[64 * 72];   // [d][s]
  __shared__ bf16_t ls_pk[128 * 72];  // rel-pos rows; first 64 rows reused as P
  __shared__ bf16_t ls_r[64 * 132];   // Bt block (bf16)
  bf16_t* const ls_p = ls_pk;         // alias: pk reads finish before P writes

  const int tid = threadIdx.x, w = tid >> 6, lane = tid & 63;
  const int lanelo = lane & 15, quad = lane >> 4;
  const int t0 = blockIdx.x * 64;
  const int bh = blockIdx.y, bb = bh >> 2, h = bh & 3;
  const size_t rowbase = (size_t)bb * T_;

  // stage q tile once
  for (int c = tid; c < 64 * 8; c += 256) {
    int r = c >> 3, c8 = (c & 7) * 8;
    *(bf16x8*)&ls_q[r * 72 + c8] =
        *(const bf16x8*)(qkv + (rowbase + t0 + r) * 768 + h * 64 + c8);
  }
  __syncthreads();
  bf16x8 qf[2];
  qf[0] = *(const bf16x8*)&ls_q[(w * 16 + lanelo) * 72 + quad * 8];
  qf[1] = *(const bf16x8*)&ls_q[(w * 16 + lanelo) * 72 + 32 + quad * 8];

  f32x4 o_acc[4] = {};
  float m_run[4], l_run[4];
#pragma unroll
  for (int i = 0; i < 4; ++i) { m_run[i] = -__builtin_inff(); l_run[i] = 0.f; }

  for (int st = 0; st < T_ / 64; ++st) {
    const int s0 = st * 64;
    __syncthreads();  // previous iteration fully consumed LDS
    // stage K tile
    for (int c = tid; c < 64 * 8; c += 256) {
      int r = c >> 3, c8 = (c & 7) * 8;
      *(bf16x8*)&ls_k[r * 72 + c8] =
          *(const bf16x8*)(qkv + (rowbase + s0 + r) * 768 + 256 + h * 64 + c8);
    }
    // stage V transposed [d][s]
    for (int c = tid; c < 64 * 8; c += 256) {
      int r = c >> 3, d0 = (c & 7) * 8;
      bf16x8 vv = *(const bf16x8*)(qkv + (rowbase + s0 + r) * 768 + 512 + h * 64 + d0);
#pragma unroll
      for (int i = 0; i < 8; ++i) ls_vt[(d0 + i) * 72 + r] = vv[i];
    }
    // stage rel-pos rows: j in [0,128), rel = t - s + 1000 = base + j
    {
      const int base = t0 - s0 + 937;  // 1000 - 63
      for (int c = tid; c < 128 * 8; c += 256) {
        int r = c >> 3, c8 = (c & 7) * 8;
        *(bf16x8*)&ls_pk[r * 72 + c8] =
            *(const bf16x8*)(pkn + (size_t)(base + r) * DK + c8);
      }
    }
    __syncthreads();

    // R GEMM: R[t,j] = q[t] . pknrow[j]   (j = (t-t0)-(s-s0)+63)
    {
      f32x4 racc[8] = {};
#pragma unroll
      for (int kk = 0; kk < 2; ++kk) {
#pragma unroll
        for (int jf = 0; jf < 8; ++jf) {
          bf16x8 bfr = *(const bf16x8*)&ls_pk[(jf * 16 + lanelo) * 72 + kk * 32 + quad * 8];
          racc[jf] = mfma16(qf[kk], bfr, racc[jf]);
        }
      }
#pragma unroll
      for (int jf = 0; jf < 8; ++jf)
#pragma unroll
        for (int reg = 0; reg < 4; ++reg)
          ls_r[(w * 16 + quad * 4 + reg) * 132 + jf * 16 + lanelo] =
              (bf16_t)racc[jf][reg];
    }
    __syncthreads();  // all pk reads done -> safe to overwrite ls_p later

    // S GEMM
    f32x4 sacc[4] = {};
#pragma unroll
    for (int kk = 0; kk < 2; ++kk) {
#pragma unroll
      for (int nf = 0; nf < 4; ++nf) {
        bf16x8 bk = *(const bf16x8*)&ls_k[(nf * 16 + lanelo) * 72 + kk * 32 + quad * 8];
        sacc[nf] = mfma16(qf[kk], bk, sacc[nf]);
      }
    }
    // add Bt, scale, mask
    float sv[4][4], pmask[4];
#pragma unroll
    for (int nf = 0; nf < 4; ++nf) {
      const int scol = nf * 16 + lanelo;
      const int mk = masks[bb * T_ + s0 + scol];
      pmask[nf] = mk ? 1.f : 0.f;
#pragma unroll
      for (int reg = 0; reg < 4; ++reg) {
        const int trow = w * 16 + quad * 4 + reg;
        const float bt = (float)ls_r[trow * 132 + (trow - scol + 63)];
        const float val = (sacc[nf][reg] + bt) * 0.125f;
        sv[nf][reg] = mk ? val : -3.4028235e38f;
      }
    }
    // online softmax update (rows live across 16 lanes of the quad's cols)
    float alpha[4];
#pragma unroll
    for (int reg = 0; reg < 4; ++reg) {
      float bm = fmaxf(fmaxf(sv[0][reg], sv[1][reg]), fmaxf(sv[2][reg], sv[3][reg]));
#pragma unroll
      for (int o = 1; o < 16; o <<= 1) bm = fmaxf(bm, __shfl_xor(bm, o));
      const float mn = fmaxf(m_run[reg], bm);
      alpha[reg] = __expf(m_run[reg] - mn);
      m_run[reg] = mn;
      float rsum = 0.f;
#pragma unroll
      for (int nf = 0; nf < 4; ++nf) {
        float p = __expf(sv[nf][reg] - mn) * pmask[nf];
        sv[nf][reg] = p;
        rsum += p;
      }
#pragma unroll
      for (int o = 1; o < 16; o <<= 1) rsum += __shfl_xor(rsum, o);
      l_run[reg] = l_run[reg] * alpha[reg] + rsum;
    }
#pragma unroll
    for (int nf = 0; nf < 4; ++nf)
#pragma unroll
      for (int reg = 0; reg < 4; ++reg) {
        o_acc[nf][reg] *= alpha[reg];
        ls_p[(w * 16 + quad * 4 + reg) * 72 + nf * 16 + lanelo] = (bf16_t)sv[nf][reg];
      }
    // PV (same-wave LDS RAW on ls_p: DS in-order per wave)
#pragma unroll
    for (int kk = 0; kk < 2; ++kk) {
      bf16x8 ap = *(const bf16x8*)&ls_p[(w * 16 + lanelo) * 72 + kk * 32 + quad * 8];
#pragma unroll
      for (int nf = 0; nf < 4; ++nf) {
        bf16x8 bv = *(const bf16x8*)&ls_vt[(nf * 16 + lanelo) * 72 + kk * 32 + quad * 8];
        o_acc[nf] = mfma16(ap, bv, o_acc[nf]);
      }
    }
  }

#pragma unroll
  for (int reg = 0; reg < 4; ++reg) {
    const float li = l_run[reg];
    const float linv = (li > 0.f) ? 1.f / li : 0.f;
#pragma unroll
    for (int nf = 0; nf < 4; ++nf) {
      const size_t orow = rowbase + t0 + w * 16 + quad * 4 + reg;
      out[orow * D_ + h * 64 + nf * 16 + lanelo] = (bf16_t)(o_acc[nf][reg] * linv);
    }
  }
}

// ---------------------------------------------------------------------------
// host
// ---------------------------------------------------------------------------
extern "C" void kernel_launch(void* const* d_in, const int* in_sizes, int n_in,
                              void* d_out, int out_size, void* d_ws, size_t ws_size,
                              hipStream_t stream) {
  const float* xs       = (const float*)d_in[0];
  const int*   masks    = (const int*)d_in[1];
  const float* emb_w    = (const float*)d_in[2];
  const float* emb_b    = (const float*)d_in[3];
  const float* emb_g    = (const float*)d_in[4];
  const float* emb_beta = (const float*)d_in[5];
  const float* pe_k     = (const float*)d_in[6];
  const float* Wq       = (const float*)d_in[7];
  const float* bq       = (const float*)d_in[8];
  const float* Wk       = (const float*)d_in[9];
  const float* bk       = (const float*)d_in[10];
  const float* Wv       = (const float*)d_in[11];
  const float* bv       = (const float*)d_in[12];
  const float* Wo       = (const float*)d_in[13];
  const float* bo       = (const float*)d_in[14];
  const float* ln1_g    = (const float*)d_in[15];
  const float* ln1_b    = (const float*)d_in[16];
  const float* ln2_g    = (const float*)d_in[17];
  const float* ln2_b    = (const float*)d_in[18];
  const float* lnk_g    = (const float*)d_in[19];
  const float* lnk_b    = (const float*)d_in[20];
  const float* W1       = (const float*)d_in[21];
  const float* b1       = (const float*)d_in[22];
  const float* W2       = (const float*)d_in[23];
  const float* b2       = (const float*)d_in[24];
  const float* after_g  = (const float*)d_in[25];
  const float* after_b  = (const float*)d_in[26];

  char* ws = (char*)d_ws;
  size_t off = 0;
  auto take = [&](size_t bytes) -> void* {
    void* p = ws + off;
    off += (bytes + 255) & ~(size_t)255;
    return p;
  };
  bf16_t* ewb  = (bf16_t*)take((size_t)D_ * KPAD * 2);
  bf16_t* wcat = (bf16_t*)take((size_t)L_ * 768 * D_ * 2);
  float*  bcat = (float*) take((size_t)L_ * 768 * 4);
  bf16_t* wob  = (bf16_t*)take((size_t)L_ * D_ * D_ * 2);
  bf16_t* w1b  = (bf16_t*)take((size_t)L_ * FF_ * D_ * 2);
  bf16_t* w2b  = (bf16_t*)take((size_t)L_ * D_ * FF_ * 2);
  bf16_t* pknb = (bf16_t*)take((size_t)L_ * PKROWS * DK * 2);
  float*  x    = (float*) take((size_t)NROW * D_ * 4);
  bf16_t* y    = (bf16_t*)take((size_t)NROW * D_ * 2);
  bf16_t* qkv  = (bf16_t*)take((size_t)NROW * 768 * 2);
  bf16_t* ao   = (bf16_t*)take((size_t)NROW * D_ * 2);
  bf16_t* hbuf = (bf16_t*)take((size_t)NROW * FF_ * 2);
  bf16_t* xsb  = hbuf;          // alias: xs_bf16 only needed before first FF1
  float*  tmp  = (float*)qkv;   // alias: embed pre-LN only needed before first QKV

  // bf16 conversions / packing (done every call; inputs restored each launch)
  cvt_pad_row<<<NROW, 256, 0, stream>>>(xs, xsb, IDIM, KPAD);
  cvt_pad_row<<<D_, 256, 0, stream>>>(emb_w, ewb, IDIM, KPAD);
  pack_qkvw<<<2048, 256, 0, stream>>>(Wq, Wk, Wv, wcat);
  pack_qkvb<<<48, 256, 0, stream>>>(bq, bk, bv, bcat);
  cvt_f32_bf16<<<1024, 256, 0, stream>>>(Wo, wob, L_ * D_ * D_);
  cvt_f32_bf16<<<2048, 256, 0, stream>>>(W1, w1b, L_ * FF_ * D_);
  cvt_f32_bf16<<<2048, 256, 0, stream>>>(W2, w2b, L_ * D_ * FF_);
  pkn_ln<<<(L_ * PKROWS) / 4, 256, 0, stream>>>(pe_k, lnk_g, lnk_b, pknb);

  // embed: GEMM (+bias) -> LN -> ReLU -> x (fp32)
  gemm_bf16<64, 64, 0><<<dim3(NROW / 64, D_ / 64), 256, 0, stream>>>(
      xsb, KPAD, ewb, KPAD, emb_b, tmp, D_, nullptr, KPAD);
  ln_rows<false, true><<<NROW / 4, 256, 0, stream>>>(tmp, emb_g, emb_beta, x);

  for (int l = 0; l < L_; ++l) {
    ln_rows<true, false><<<NROW / 4, 256, 0, stream>>>(x, ln1_g + l * D_, ln1_b + l * D_, y);
    gemm_bf16<64, 64, 1><<<dim3(NROW / 64, 768 / 64), 256, 0, stream>>>(
        y, D_, wcat + (size_t)l * 768 * D_, D_, bcat + l * 768, qkv, 768, nullptr, D_);
    attn_fused<<<dim3(T_ / 64, B_ * H_), 256, 0, stream>>>(
        qkv, pknb + (size_t)l * PKROWS * DK, masks, ao);
    gemm_bf16<64, 64, 3><<<dim3(NROW / 64, D_ / 64), 256, 0, stream>>>(
        ao, D_, wob + (size_t)l * D_ * D_, D_, bo + l * D_, x, D_, x, D_);
    ln_rows<true, false><<<NROW / 4, 256, 0, stream>>>(x, ln2_g + l * D_, ln2_b + l * D_, y);
    gemm_bf16<128, 128, 2><<<dim3(NROW / 128, FF_ / 128), 256, 0, stream>>>(
        y, D_, w1b + (size_t)l * FF_ * D_, D_, b1 + l * FF_, hbuf, FF_, nullptr, D_);
    gemm_bf16<64, 64, 3><<<dim3(NROW / 64, D_ / 64), 256, 0, stream>>>(
        hbuf, FF_, w2b + (size_t)l * D_ * FF_, FF_, b2 + l * D_, x, D_, x, FF_);
  }
  ln_rows<false, false><<<NROW / 4, 256, 0, stream>>>(x, after_g, after_b, (float*)d_out);
}

// Round 2
// 1545.080 us; speedup vs baseline: 1.1030x; 1.1030x over previous
//
#include <hip/hip_runtime.h>
#include <cstdint>

// ---------------------------------------------------------------------------
// EETransformerEncoder on MI355X (gfx950).  Round 2.
// - attention: flash w/ s-split=4 (grid 1024), LDS 53.76KB -> 3 blocks/CU,
//   conflict-free R^T (LD=66) + conflict-free V^T staging.
// - Wo/FF2/embed GEMMs: split-K=2, fp32 partials; combine kernel fuses
//   bias + residual + LayerNorm (removes ln1/ln2 launches).
// ---------------------------------------------------------------------------

typedef __bf16 bf16_t;
typedef bf16_t bf16x4 __attribute__((ext_vector_type(4)));
typedef bf16_t bf16x8 __attribute__((ext_vector_type(8)));
typedef float  f32x4  __attribute__((ext_vector_type(4)));

#define B_    8
#define T_    512
#define IDIM  1799
#define KPAD  1824        // 57*32
#define D_    256
#define H_    4
#define DK    64
#define FF_   2048
#define L_    16
#define NROW  4096        // B_*T_
#define PKROWS 2000       // 2*MAXLEN
#define NBH   32          // B_*H_
#define NSA   4           // attention s-splits

__device__ __forceinline__ f32x4 mfma16(bf16x8 a, bf16x8 b, f32x4 c) {
  return __builtin_amdgcn_mfma_f32_16x16x32_bf16(a, b, c, 0, 0, 0);
}

__device__ __forceinline__ void async_cp16(const void* g, void* l) {
  __builtin_amdgcn_global_load_lds(
      (__attribute__((address_space(1))) void*)(g),
      (__attribute__((address_space(3))) void*)(l), 16, 0, 0);
}

// ---------------------------------------------------------------------------
// conversions / packing
// ---------------------------------------------------------------------------
__global__ __launch_bounds__(256) void cvt_f32_bf16(const float* __restrict__ s,
                                                    bf16_t* __restrict__ d, int n) {
  int i = blockIdx.x * 256 + threadIdx.x;
  int stride = gridDim.x * 256;
  for (; i < n; i += stride) d[i] = (bf16_t)s[i];
}

__global__ __launch_bounds__(256) void cvt_pad_row(const float* __restrict__ s,
                                                   bf16_t* __restrict__ d,
                                                   int ksrc, int kdst) {
  const int r = blockIdx.x;
  const float* sr = s + (size_t)r * ksrc;
  bf16_t* dr = d + (size_t)r * kdst;
  for (int k = threadIdx.x; k < kdst; k += 256)
    dr[k] = (k < ksrc) ? (bf16_t)sr[k] : (bf16_t)0.f;
}

__global__ __launch_bounds__(256) void pack_qkvw(const float* __restrict__ wq,
                                                 const float* __restrict__ wk,
                                                 const float* __restrict__ wv,
                                                 bf16_t* __restrict__ dst) {
  const int per_l = 768 * 256;
  int i = blockIdx.x * 256 + threadIdx.x;
  int stride = gridDim.x * 256;
  for (; i < L_ * per_l; i += stride) {
    int l = i / per_l, r = i - l * per_l;
    int n = r >> 8, c = r & 255;
    int sel = n >> 8, nn = n & 255;
    const float* w = (sel == 0) ? wq : (sel == 1) ? wk : wv;
    dst[i] = (bf16_t)w[((size_t)l * 256 + nn) * 256 + c];
  }
}

__global__ __launch_bounds__(256) void pack_qkvb(const float* __restrict__ bq,
                                                 const float* __restrict__ bk,
                                                 const float* __restrict__ bv,
                                                 float* __restrict__ dst) {
  int i = blockIdx.x * 256 + threadIdx.x;
  if (i >= L_ * 768) return;
  int l = i / 768, n = i - l * 768;
  int sel = n >> 8, nn = n & 255;
  const float* b = (sel == 0) ? bq : (sel == 1) ? bk : bv;
  dst[i] = b[l * 256 + nn];
}

__global__ __launch_bounds__(256) void pkn_ln(const float* __restrict__ pe_k,
                                              const float* __restrict__ lnk_g,
                                              const float* __restrict__ lnk_b,
                                              bf16_t* __restrict__ out) {
  const int idx = blockIdx.x * 4 + (threadIdx.x >> 6);
  if (idx >= L_ * PKROWS) return;
  const int lane = threadIdx.x & 63;
  const int l = idx / PKROWS, r = idx - l * PKROWS;
  float v = pe_k[(size_t)r * DK + lane];
  float s = v;
#pragma unroll
  for (int o = 32; o; o >>= 1) s += __shfl_xor(s, o);
  const float mean = s * (1.f / DK);
  const float dx = v - mean;
  float q = dx * dx;
#pragma unroll
  for (int o = 32; o; o >>= 1) q += __shfl_xor(q, o);
  const float rs = rsqrtf(q * (1.f / DK) + 1e-12f);
  out[((size_t)l * PKROWS + r) * DK + lane] =
      (bf16_t)(dx * rs * lnk_g[l * DK + lane] + lnk_b[l * DK + lane]);
}

// ---------------------------------------------------------------------------
// LayerNorm over rows of 256 (one wave per row)
// ---------------------------------------------------------------------------
template <bool BF16OUT, bool RELU>
__global__ __launch_bounds__(256) void ln_rows(const float* __restrict__ src,
                                               const float* __restrict__ g,
                                               const float* __restrict__ b,
                                               void* __restrict__ dst) {
  const int row = blockIdx.x * 4 + (threadIdx.x >> 6);
  const int lane = threadIdx.x & 63;
  const float4 v = ((const float4*)(src + (size_t)row * D_))[lane];
  float s = v.x + v.y + v.z + v.w;
#pragma unroll
  for (int o = 32; o; o >>= 1) s += __shfl_xor(s, o);
  const float mean = s * (1.f / D_);
  const float d0 = v.x - mean, d1 = v.y - mean, d2 = v.z - mean, d3 = v.w - mean;
  float q = d0 * d0 + d1 * d1 + d2 * d2 + d3 * d3;
#pragma unroll
  for (int o = 32; o; o >>= 1) q += __shfl_xor(q, o);
  const float rs = rsqrtf(q * (1.f / D_) + 1e-12f);
  const float4 gg = ((const float4*)g)[lane];
  const float4 bb = ((const float4*)b)[lane];
  float o0 = d0 * rs * gg.x + bb.x;
  float o1 = d1 * rs * gg.y + bb.y;
  float o2 = d2 * rs * gg.z + bb.z;
  float o3 = d3 * rs * gg.w + bb.w;
  if (RELU) {
    o0 = fmaxf(o0, 0.f); o1 = fmaxf(o1, 0.f);
    o2 = fmaxf(o2, 0.f); o3 = fmaxf(o3, 0.f);
  }
  if (BF16OUT) {
    bf16x4 o4 = {(bf16_t)o0, (bf16_t)o1, (bf16_t)o2, (bf16_t)o3};
    ((bf16x4*)((bf16_t*)dst + (size_t)row * D_))[lane] = o4;
  } else {
    ((float4*)((float*)dst + (size_t)row * D_))[lane] = make_float4(o0, o1, o2, o3);
  }
}

// ---------------------------------------------------------------------------
// combine for split-K GEMM partials: x = x + sum(parts) + bias; y = LN(x)
// one wave per row of 256
// ---------------------------------------------------------------------------
template <int NS, bool WRITE_Y>
__global__ __launch_bounds__(256) void add_combine_ln(
    const float* __restrict__ parts, const float* __restrict__ bias,
    float* __restrict__ x, const float* __restrict__ g,
    const float* __restrict__ b, bf16_t* __restrict__ y) {
  const int row = blockIdx.x * 4 + (threadIdx.x >> 6);
  const int lane = threadIdx.x & 63;
  const size_t idx = (size_t)row * 64 + lane;
  float4 v = ((const float4*)x)[idx];
#pragma unroll
  for (int p = 0; p < NS; ++p) {
    float4 pv = ((const float4*)parts)[(size_t)p * NROW * 64 + idx];
    v.x += pv.x; v.y += pv.y; v.z += pv.z; v.w += pv.w;
  }
  const float4 bi = ((const float4*)bias)[lane];
  v.x += bi.x; v.y += bi.y; v.z += bi.z; v.w += bi.w;
  ((float4*)x)[idx] = v;
  if (WRITE_Y) {
    float s = v.x + v.y + v.z + v.w;
#pragma unroll
    for (int o = 32; o; o >>= 1) s += __shfl_xor(s, o);
    const float mean = s * (1.f / D_);
    const float d0 = v.x - mean, d1 = v.y - mean, d2 = v.z - mean, d3 = v.w - mean;
    float q = d0 * d0 + d1 * d1 + d2 * d2 + d3 * d3;
#pragma unroll
    for (int o = 32; o; o >>= 1) q += __shfl_xor(q, o);
    const float rs = rsqrtf(q * (1.f / D_) + 1e-12f);
    const float4 gg = ((const float4*)g)[lane];
    const float4 bb = ((const float4*)b)[lane];
    bf16x4 o4 = {(bf16_t)(d0 * rs * gg.x + bb.x), (bf16_t)(d1 * rs * gg.y + bb.y),
                 (bf16_t)(d2 * rs * gg.z + bb.z), (bf16_t)(d3 * rs * gg.w + bb.w)};
    ((bf16x4*)y)[idx] = o4;
  }
}

// embed combine: x = relu(LN(sum(parts)+bias))
__global__ __launch_bounds__(256) void embed_combine(
    const float* __restrict__ parts, const float* __restrict__ bias,
    const float* __restrict__ g, const float* __restrict__ b,
    float* __restrict__ x) {
  const int row = blockIdx.x * 4 + (threadIdx.x >> 6);
  const int lane = threadIdx.x & 63;
  const size_t idx = (size_t)row * 64 + lane;
  float4 v = ((const float4*)parts)[idx];
  float4 p1 = ((const float4*)parts)[(size_t)NROW * 64 + idx];
  const float4 bi = ((const float4*)bias)[lane];
  v.x += p1.x + bi.x; v.y += p1.y + bi.y; v.z += p1.z + bi.z; v.w += p1.w + bi.w;
  float s = v.x + v.y + v.z + v.w;
#pragma unroll
  for (int o = 32; o; o >>= 1) s += __shfl_xor(s, o);
  const float mean = s * (1.f / D_);
  const float d0 = v.x - mean, d1 = v.y - mean, d2 = v.z - mean, d3 = v.w - mean;
  float q = d0 * d0 + d1 * d1 + d2 * d2 + d3 * d3;
#pragma unroll
  for (int o = 32; o; o >>= 1) q += __shfl_xor(q, o);
  const float rs = rsqrtf(q * (1.f / D_) + 1e-12f);
  const float4 gg = ((const float4*)g)[lane];
  const float4 bb = ((const float4*)b)[lane];
  ((float4*)x)[idx] = make_float4(
      fmaxf(d0 * rs * gg.x + bb.x, 0.f), fmaxf(d1 * rs * gg.y + bb.y, 0.f),
      fmaxf(d2 * rs * gg.z + bb.z, 0.f), fmaxf(d3 * rs * gg.w + bb.w, 0.f));
}

// ---------------------------------------------------------------------------
// bf16 NT GEMM: C[M,N] = A[M,K] * B[N,K]^T, split-K via blockIdx.z.
// EP: 0 f32 bias; 1 bf16 bias; 2 bf16 bias+relu; 3 f32 bias+resid;
//     4 f32 raw partial (no bias) at Cout + z*zstride
// ---------------------------------------------------------------------------
template <int BM, int BN, int EP>
__global__ __launch_bounds__(256, 2) void gemm_bf16(
    const bf16_t* __restrict__ A, int lda, const bf16_t* __restrict__ B, int ldb,
    const float* __restrict__ bias, void* __restrict__ Cout, int ldc,
    const float* __restrict__ resid, int K, size_t zstride) {
  constexpr int HM = BM / 2, HN = BN / 2;
  constexpr int FM = HM / 16, FN = HN / 16;
  constexpr int CA = (BM * 4) / 256, CB = (BN * 4) / 256;
  __shared__ bf16_t lsA[BM * 32];
  __shared__ bf16_t lsB[BN * 32];
  const int tid = threadIdx.x;
  const int w = tid >> 6, lane = tid & 63;
  const int wm = w >> 1, wn = w & 1;
  const int lanelo = lane & 15, quad = lane >> 4;
  const int wbase = tid & ~63;
  const int m0 = blockIdx.x * BM, n0 = blockIdx.y * BN;
  // K-range for this z-slice
  const int ktiles = K >> 5;
  const int tpz = (ktiles + gridDim.z - 1) / gridDim.z;
  const int kb = blockIdx.z * tpz * 32;
  const int ke = min(K, kb + tpz * 32);
  f32x4 acc[FM][FN] = {};

  for (int kt = kb; kt < ke; kt += 32) {
    __syncthreads();
#pragma unroll
    for (int rr = 0; rr < CA; ++rr) {
      int chunk = rr * 256 + tid;
      int r = chunk >> 2, qs = chunk & 3;
      int qg = qs ^ ((r >> 1) & 3);
      async_cp16(A + (size_t)(m0 + r) * lda + kt + qg * 8,
                 lsA + (size_t)(rr * 256 + wbase) * 8);
    }
#pragma unroll
    for (int rr = 0; rr < CB; ++rr) {
      int chunk = rr * 256 + tid;
      int r = chunk >> 2, qs = chunk & 3;
      int qg = qs ^ ((r >> 1) & 3);
      async_cp16(B + (size_t)(n0 + r) * ldb + kt + qg * 8,
                 lsB + (size_t)(rr * 256 + wbase) * 8);
    }
    __syncthreads();
    bf16x8 af[FM], bfv[FN];
#pragma unroll
    for (int i = 0; i < FM; ++i) {
      int r = wm * HM + i * 16 + lanelo;
      af[i] = *(const bf16x8*)(lsA + (size_t)(r * 4 + (quad ^ ((r >> 1) & 3))) * 8);
    }
#pragma unroll
    for (int j = 0; j < FN; ++j) {
      int r = wn * HN + j * 16 + lanelo;
      bfv[j] = *(const bf16x8*)(lsB + (size_t)(r * 4 + (quad ^ ((r >> 1) & 3))) * 8);
    }
#pragma unroll
    for (int i = 0; i < FM; ++i)
#pragma unroll
      for (int j = 0; j < FN; ++j) acc[i][j] = mfma16(af[i], bfv[j], acc[i][j]);
  }

#pragma unroll
  for (int i = 0; i < FM; ++i) {
#pragma unroll
    for (int j = 0; j < FN; ++j) {
#pragma unroll
      for (int reg = 0; reg < 4; ++reg) {
        const int m = m0 + wm * HM + i * 16 + quad * 4 + reg;
        const int n = n0 + wn * HN + j * 16 + lanelo;
        const size_t idx = (size_t)m * ldc + n;
        if constexpr (EP == 4) {
          ((float*)Cout + (size_t)blockIdx.z * zstride)[idx] = acc[i][j][reg];
        } else {
          float v = acc[i][j][reg] + bias[n];
          if constexpr (EP == 0) {
            ((float*)Cout)[idx] = v;
          } else if constexpr (EP == 1) {
            ((bf16_t*)Cout)[idx] = (bf16_t)v;
          } else if constexpr (EP == 2) {
            ((bf16_t*)Cout)[idx] = (bf16_t)fmaxf(v, 0.f);
          } else {
            ((float*)Cout)[idx] = v + resid[idx];
          }
        }
      }
    }
  }
}

// ---------------------------------------------------------------------------
// Attention partial: grid (T/64, NBH, NSA). Each block: 64 q-rows, 2 s-tiles.
// Writes unnormalized O (fp32) + running (m,l) per row for split combine.
// LDS 53760B -> 3 blocks/CU. R stored transposed LD=66 (conflict-free).
// ---------------------------------------------------------------------------
__global__ __launch_bounds__(256, 3) void attn_part(
    const bf16_t* __restrict__ qkv, const bf16_t* __restrict__ pkn,
    const int* __restrict__ masks, float* __restrict__ Opart,
    float* __restrict__ mpart, float* __restrict__ lpart) {
  __shared__ bf16_t ls_q[64 * 72];           // 9216 B
  __shared__ bf16_t ls_kr[128 * 66];         // 16896 B: K tile (LD72) / R^T (LD66)
  __shared__ bf16_t ls_vt[64 * 72];          // 9216 B   [d][s]
  __shared__ bf16_t ls_pk[128 * 72];         // 18432 B: pk rows / P (rows 0..63)
  bf16_t* const ls_k = ls_kr;
  bf16_t* const ls_r = ls_kr;
  bf16_t* const ls_p = ls_pk;

  const int tid = threadIdx.x, w = tid >> 6, lane = tid & 63;
  const int lanelo = lane & 15, quad = lane >> 4;
  const int t0 = blockIdx.x * 64;
  const int bh = blockIdx.y, bb = bh >> 2, h = bh & 3;
  const int z = blockIdx.z;
  const size_t rowbase = (size_t)bb * T_;

  for (int c = tid; c < 64 * 8; c += 256) {
    int r = c >> 3, c8 = (c & 7) * 8;
    *(bf16x8*)&ls_q[r * 72 + c8] =
        *(const bf16x8*)(qkv + (rowbase + t0 + r) * 768 + h * 64 + c8);
  }
  __syncthreads();
  bf16x8 qf[2];
  qf[0] = *(const bf16x8*)&ls_q[(w * 16 + lanelo) * 72 + quad * 8];
  qf[1] = *(const bf16x8*)&ls_q[(w * 16 + lanelo) * 72 + 32 + quad * 8];

  f32x4 o_acc[4] = {};
  float m_run[4], l_run[4];
#pragma unroll
  for (int i = 0; i < 4; ++i) { m_run[i] = -__builtin_inff(); l_run[i] = 0.f; }

  for (int st = 2 * z; st < 2 * z + 2; ++st) {
    const int s0 = st * 64;
    __syncthreads();  // prior-iteration LDS reads complete
    // stage K (LD 72, rows 0..63): coalesced global, conflict-free LDS
    for (int c = tid; c < 64 * 8; c += 256) {
      int r = c >> 3, c8 = (c & 7) * 8;
      *(bf16x8*)&ls_k[r * 72 + c8] =
          *(const bf16x8*)(qkv + (rowbase + s0 + r) * 768 + 256 + h * 64 + c8);
    }
    // stage V^T: lanes walk s (consecutive) -> conflict-free LDS scatter
    for (int c = tid; c < 64 * 8; c += 256) {
      int r = c & 63, d0 = (c >> 6) * 8;
      bf16x8 vv = *(const bf16x8*)(qkv + (rowbase + s0 + r) * 768 + 512 + h * 64 + d0);
#pragma unroll
      for (int i = 0; i < 8; ++i) ls_vt[(d0 + i) * 72 + r] = vv[i];
    }
    // stage rel-pos rows (128)
    {
      const int base = t0 - s0 + 937;
      for (int c = tid; c < 128 * 8; c += 256) {
        int r = c >> 3, c8 = (c & 7) * 8;
        *(bf16x8*)&ls_pk[r * 72 + c8] =
            *(const bf16x8*)(pkn + (size_t)(base + r) * DK + c8);
      }
    }
    __syncthreads();

    // S GEMM (reads q,k) and R GEMM (reads q,pk) before any LDS overwrite
    f32x4 sacc[4] = {};
#pragma unroll
    for (int kk = 0; kk < 2; ++kk)
#pragma unroll
      for (int nf = 0; nf < 4; ++nf) {
        bf16x8 bk = *(const bf16x8*)&ls_k[(nf * 16 + lanelo) * 72 + kk * 32 + quad * 8];
        sacc[nf] = mfma16(qf[kk], bk, sacc[nf]);
      }
    f32x4 racc[8] = {};
#pragma unroll
    for (int kk = 0; kk < 2; ++kk)
#pragma unroll
      for (int jf = 0; jf < 8; ++jf) {
        bf16x8 bfr = *(const bf16x8*)&ls_pk[(jf * 16 + lanelo) * 72 + kk * 32 + quad * 8];
        racc[jf] = mfma16(qf[kk], bfr, racc[jf]);
      }
    __syncthreads();  // all K/pk reads done -> ls_kr / ls_pk reusable

    // write R^T[j][t] (LD 66): banks = 33*lanelo mod 32 -> conflict-free
#pragma unroll
    for (int jf = 0; jf < 8; ++jf)
#pragma unroll
      for (int reg = 0; reg < 4; ++reg)
        ls_r[(jf * 16 + lanelo) * 66 + w * 16 + quad * 4 + reg] =
            (bf16_t)racc[jf][reg];

    // gather Bt, scale, mask (R^T read: same-wave RAW, conflict-free)
    float sv[4][4], pmask[4];
#pragma unroll
    for (int nf = 0; nf < 4; ++nf) {
      const int scol = nf * 16 + lanelo;
      const int mk = masks[bb * T_ + s0 + scol];
      pmask[nf] = mk ? 1.f : 0.f;
#pragma unroll
      for (int reg = 0; reg < 4; ++reg) {
        const int trow = w * 16 + quad * 4 + reg;
        const float bt = (float)ls_r[(trow - scol + 63) * 66 + trow];
        const float val = (sacc[nf][reg] + bt) * 0.125f;
        sv[nf][reg] = mk ? val : -3.4028235e38f;
      }
    }
    float alpha[4];
#pragma unroll
    for (int reg = 0; reg < 4; ++reg) {
      float bm = fmaxf(fmaxf(sv[0][reg], sv[1][reg]), fmaxf(sv[2][reg], sv[3][reg]));
#pragma unroll
      for (int o = 1; o < 16; o <<= 1) bm = fmaxf(bm, __shfl_xor(bm, o));
      const float mn = fmaxf(m_run[reg], bm);
      alpha[reg] = __expf(m_run[reg] - mn);
      m_run[reg] = mn;
      float rsum = 0.f;
#pragma unroll
      for (int nf = 0; nf < 4; ++nf) {
        float p = __expf(sv[nf][reg] - mn) * pmask[nf];
        sv[nf][reg] = p;
        rsum += p;
      }
#pragma unroll
      for (int o = 1; o < 16; o <<= 1) rsum += __shfl_xor(rsum, o);
      l_run[reg] = l_run[reg] * alpha[reg] + rsum;
    }
#pragma unroll
    for (int nf = 0; nf < 4; ++nf)
#pragma unroll
      for (int reg = 0; reg < 4; ++reg) {
        o_acc[nf][reg] *= alpha[reg];
        ls_p[(w * 16 + quad * 4 + reg) * 72 + nf * 16 + lanelo] = (bf16_t)sv[nf][reg];
      }
#pragma unroll
    for (int kk = 0; kk < 2; ++kk) {
      bf16x8 ap = *(const bf16x8*)&ls_p[(w * 16 + lanelo) * 72 + kk * 32 + quad * 8];
#pragma unroll
      for (int nf = 0; nf < 4; ++nf) {
        bf16x8 bv = *(const bf16x8*)&ls_vt[(nf * 16 + lanelo) * 72 + kk * 32 + quad * 8];
        o_acc[nf] = mfma16(ap, bv, o_acc[nf]);
      }
    }
  }

  // write split partials
#pragma unroll
  for (int reg = 0; reg < 4; ++reg) {
    const int trow = w * 16 + quad * 4 + reg;
    const size_t prow = ((size_t)z * NBH + bh) * T_ + t0 + trow;
#pragma unroll
    for (int nf = 0; nf < 4; ++nf)
      Opart[prow * 64 + nf * 16 + lanelo] = o_acc[nf][reg];
    if (lanelo == 0) { mpart[prow] = m_run[reg]; lpart[prow] = l_run[reg]; }
  }
}

// combine attention splits -> ao bf16 [4096,256]
__global__ __launch_bounds__(256) void attn_combine(
    const float* __restrict__ Opart, const float* __restrict__ mpart,
    const float* __restrict__ lpart, bf16_t* __restrict__ ao) {
  const int hr = blockIdx.x * 4 + (threadIdx.x >> 6);  // 0..NBH*T-1
  const int lane = threadIdx.x & 63;
  const int bh = hr >> 9, t = hr & 511;
  float mp[NSA], lp[NSA];
  float m = -__builtin_inff();
#pragma unroll
  for (int p = 0; p < NSA; ++p) {
    const size_t prow = ((size_t)p * NBH + bh) * T_ + t;
    mp[p] = mpart[prow]; lp[p] = lpart[prow];
    m = fmaxf(m, mp[p]);
  }
  float denom = 0.f, o = 0.f;
#pragma unroll
  for (int p = 0; p < NSA; ++p) {
    if (lp[p] > 0.f) {
      const float wp = __expf(mp[p] - m);
      denom += lp[p] * wp;
      o += Opart[(((size_t)p * NBH + bh) * T_ + t) * 64 + lane] * wp;
    }
  }
  const float res = (denom > 0.f) ? o / denom : 0.f;
  const int bb = bh >> 2, hh = bh & 3;
  ao[((size_t)bb * T_ + t) * D_ + hh * 64 + lane] = (bf16_t)res;
}

// ---------------------------------------------------------------------------
// host
// ---------------------------------------------------------------------------
extern "C" void kernel_launch(void* const* d_in, const int* in_sizes, int n_in,
                              void* d_out, int out_size, void* d_ws, size_t ws_size,
                              hipStream_t stream) {
  const float* xs       = (const float*)d_in[0];
  const int*   masks    = (const int*)d_in[1];
  const float* emb_w    = (const float*)d_in[2];
  const float* emb_b    = (const float*)d_in[3];
  const float* emb_g    = (const float*)d_in[4];
  const float* emb_beta = (const float*)d_in[5];
  const float* pe_k     = (const float*)d_in[6];
  const float* Wq       = (const float*)d_in[7];
  const float* bq       = (const float*)d_in[8];
  const float* Wk       = (const float*)d_in[9];
  const float* bk       = (const float*)d_in[10];
  const float* Wv       = (const float*)d_in[11];
  const float* bv       = (const float*)d_in[12];
  const float* Wo       = (const float*)d_in[13];
  const float* bo       = (const float*)d_in[14];
  const float* ln1_g    = (const float*)d_in[15];
  const float* ln1_b    = (const float*)d_in[16];
  const float* ln2_g    = (const float*)d_in[17];
  const float* ln2_b    = (const float*)d_in[18];
  const float* lnk_g    = (const float*)d_in[19];
  const float* lnk_b    = (const float*)d_in[20];
  const float* W1       = (const float*)d_in[21];
  const float* b1       = (const float*)d_in[22];
  const float* W2       = (const float*)d_in[23];
  const float* b2       = (const float*)d_in[24];
  const float* after_g  = (const float*)d_in[25];
  const float* after_b  = (const float*)d_in[26];

  char* ws = (char*)d_ws;
  size_t off = 0;
  auto take = [&](size_t bytes) -> void* {
    void* p = ws + off;
    off += (bytes + 255) & ~(size_t)255;
    return p;
  };
  bf16_t* ewb  = (bf16_t*)take((size_t)D_ * KPAD * 2);
  bf16_t* wcat = (bf16_t*)take((size_t)L_ * 768 * D_ * 2);
  float*  bcat = (float*) take((size_t)L_ * 768 * 4);
  bf16_t* wob  = (bf16_t*)take((size_t)L_ * D_ * D_ * 2);
  bf16_t* w1b  = (bf16_t*)take((size_t)L_ * FF_ * D_ * 2);
  bf16_t* w2b  = (bf16_t*)take((size_t)L_ * D_ * FF_ * 2);
  bf16_t* pknb = (bf16_t*)take((size_t)L_ * PKROWS * DK * 2);
  float*  x    = (float*) take((size_t)NROW * D_ * 4);
  bf16_t* y    = (bf16_t*)take((size_t)NROW * D_ * 2);
  bf16_t* qkv  = (bf16_t*)take((size_t)NROW * 768 * 2);
  bf16_t* ao   = (bf16_t*)take((size_t)NROW * D_ * 2);
  bf16_t* hbuf = (bf16_t*)take((size_t)NROW * FF_ * 2);
  // shared scratch region: attn partials OR split-K GEMM partials (disjoint use)
  float*  Opart = (float*)take((size_t)NSA * NBH * T_ * 64 * 4);  // 16.78 MB
  float*  mpart = (float*)take((size_t)NSA * NBH * T_ * 4);
  float*  lpart = (float*)take((size_t)NSA * NBH * T_ * 4);
  float*  gpart = Opart;        // alias: 2 * NROW*256 fp32 = 8 MB <= Opart
  bf16_t* xsb  = hbuf;          // xs bf16 (14.9MB) only needed before first FF1
  const size_t ZS = (size_t)NROW * D_;  // split partial stride (elements)

  // prep
  cvt_pad_row<<<NROW, 256, 0, stream>>>(xs, xsb, IDIM, KPAD);
  cvt_pad_row<<<D_, 256, 0, stream>>>(emb_w, ewb, IDIM, KPAD);
  pack_qkvw<<<2048, 256, 0, stream>>>(Wq, Wk, Wv, wcat);
  pack_qkvb<<<48, 256, 0, stream>>>(bq, bk, bv, bcat);
  cvt_f32_bf16<<<1024, 256, 0, stream>>>(Wo, wob, L_ * D_ * D_);
  cvt_f32_bf16<<<2048, 256, 0, stream>>>(W1, w1b, L_ * FF_ * D_);
  cvt_f32_bf16<<<2048, 256, 0, stream>>>(W2, w2b, L_ * D_ * FF_);
  pkn_ln<<<(L_ * PKROWS) / 4, 256, 0, stream>>>(pe_k, lnk_g, lnk_b, pknb);

  // embed: split-K=2 GEMM -> combine(LN+relu) -> x; then ln1 layer0 -> y
  gemm_bf16<64, 64, 4><<<dim3(NROW / 64, D_ / 64, 2), 256, 0, stream>>>(
      xsb, KPAD, ewb, KPAD, nullptr, gpart, D_, nullptr, KPAD, ZS);
  embed_combine<<<NROW / 4, 256, 0, stream>>>(gpart, emb_b, emb_g, emb_beta, x);
  ln_rows<true, false><<<NROW / 4, 256, 0, stream>>>(x, ln1_g, ln1_b, y);

  for (int l = 0; l < L_; ++l) {
    // QKV projection
    gemm_bf16<64, 64, 1><<<dim3(NROW / 64, 768 / 64), 256, 0, stream>>>(
        y, D_, wcat + (size_t)l * 768 * D_, D_, bcat + l * 768, qkv, 768, nullptr,
        D_, 0);
    // attention (s-split 4) + combine
    attn_part<<<dim3(T_ / 64, NBH, NSA), 256, 0, stream>>>(
        qkv, pknb + (size_t)l * PKROWS * DK, masks, Opart, mpart, lpart);
    attn_combine<<<NBH * T_ / 4, 256, 0, stream>>>(Opart, mpart, lpart, ao);
    // Wo (split-K=2) + combine(resid+bias) fused with ln2 -> x, y
    gemm_bf16<64, 64, 4><<<dim3(NROW / 64, D_ / 64, 2), 256, 0, stream>>>(
        ao, D_, wob + (size_t)l * D_ * D_, D_, nullptr, gpart, D_, nullptr, D_, ZS);
    add_combine_ln<2, true><<<NROW / 4, 256, 0, stream>>>(
        gpart, bo + l * D_, x, ln2_g + l * D_, ln2_b + l * D_, y);
    // FF1
    gemm_bf16<128, 128, 2><<<dim3(NROW / 128, FF_ / 128), 256, 0, stream>>>(
        y, D_, w1b + (size_t)l * FF_ * D_, D_, b1 + l * FF_, hbuf, FF_, nullptr,
        D_, 0);
    // FF2 (split-K=2) + combine(resid+bias) fused with next layer's ln1 -> x, y
    gemm_bf16<64, 64, 4><<<dim3(NROW / 64, D_ / 64, 2), 256, 0, stream>>>(
        hbuf, FF_, w2b + (size_t)l * D_ * FF_, FF_, nullptr, gpart, D_, nullptr,
        FF_, ZS);
    if (l < L_ - 1) {
      add_combine_ln<2, true><<<NROW / 4, 256, 0, stream>>>(
          gpart, b2 + l * D_, x, ln1_g + (l + 1) * D_, ln1_b + (l + 1) * D_, y);
    } else {
      add_combine_ln<2, false><<<NROW / 4, 256, 0, stream>>>(
          gpart, b2 + l * D_, x, nullptr, nullptr, nullptr);
    }
  }
  ln_rows<false, false><<<NROW / 4, 256, 0, stream>>>(x, after_g, after_b,
                                                      (float*)d_out);
}

// Round 3
// 1436.001 us; speedup vs baseline: 1.1868x; 1.0760x over previous
//
#include <hip/hip_runtime.h>
#include <cstdint>

// ---------------------------------------------------------------------------
// EETransformerEncoder on MI355X (gfx950).  Round 3.
// - rel-pos bias Bt[t,s]=q.pkn[t-s+1000] precomputed per layer by bt_gemm
//   (bf16 in HBM) -> attention is pure flash: 2 barriers/s-tile, 4 blocks/CU.
// - all GEMMs BK=64 (halved barriers), async global_load_lds staging with
//   XOR(r&7) chunk swizzle (conflict-floor ds_read_b128).
// - attention split partials bf16 (half the combine traffic).
// ---------------------------------------------------------------------------

typedef __bf16 bf16_t;
typedef bf16_t bf16x4 __attribute__((ext_vector_type(4)));
typedef bf16_t bf16x8 __attribute__((ext_vector_type(8)));
typedef float  f32x4  __attribute__((ext_vector_type(4)));

#define B_    8
#define T_    512
#define IDIM  1799
#define KPAD  1856        // 29*64
#define D_    256
#define H_    4
#define DK    64
#define FF_   2048
#define L_    16
#define NROW  4096        // B_*T_
#define PKROWS 2000       // 2*MAXLEN
#define NBH   32          // B_*H_
#define NSA   4           // attention s-splits

__device__ __forceinline__ f32x4 mfma16(bf16x8 a, bf16x8 b, f32x4 c) {
  return __builtin_amdgcn_mfma_f32_16x16x32_bf16(a, b, c, 0, 0, 0);
}

__device__ __forceinline__ void async_cp16(const void* g, void* l) {
  __builtin_amdgcn_global_load_lds(
      (__attribute__((address_space(1))) void*)(g),
      (__attribute__((address_space(3))) void*)(l), 16, 0, 0);
}

// ---------------------------------------------------------------------------
// conversions / packing
// ---------------------------------------------------------------------------
__global__ __launch_bounds__(256) void cvt_f32_bf16(const float* __restrict__ s,
                                                    bf16_t* __restrict__ d, int n) {
  int i = blockIdx.x * 256 + threadIdx.x;
  int stride = gridDim.x * 256;
  for (; i < n; i += stride) d[i] = (bf16_t)s[i];
}

__global__ __launch_bounds__(256) void cvt_pad_row(const float* __restrict__ s,
                                                   bf16_t* __restrict__ d,
                                                   int ksrc, int kdst) {
  const int r = blockIdx.x;
  const float* sr = s + (size_t)r * ksrc;
  bf16_t* dr = d + (size_t)r * kdst;
  for (int k = threadIdx.x; k < kdst; k += 256)
    dr[k] = (k < ksrc) ? (bf16_t)sr[k] : (bf16_t)0.f;
}

__global__ __launch_bounds__(256) void pack_qkvw(const float* __restrict__ wq,
                                                 const float* __restrict__ wk,
                                                 const float* __restrict__ wv,
                                                 bf16_t* __restrict__ dst) {
  const int per_l = 768 * 256;
  int i = blockIdx.x * 256 + threadIdx.x;
  int stride = gridDim.x * 256;
  for (; i < L_ * per_l; i += stride) {
    int l = i / per_l, r = i - l * per_l;
    int n = r >> 8, c = r & 255;
    int sel = n >> 8, nn = n & 255;
    const float* w = (sel == 0) ? wq : (sel == 1) ? wk : wv;
    dst[i] = (bf16_t)w[((size_t)l * 256 + nn) * 256 + c];
  }
}

__global__ __launch_bounds__(256) void pack_qkvb(const float* __restrict__ bq,
                                                 const float* __restrict__ bk,
                                                 const float* __restrict__ bv,
                                                 float* __restrict__ dst) {
  int i = blockIdx.x * 256 + threadIdx.x;
  if (i >= L_ * 768) return;
  int l = i / 768, n = i - l * 768;
  int sel = n >> 8, nn = n & 255;
  const float* b = (sel == 0) ? bq : (sel == 1) ? bk : bv;
  dst[i] = b[l * 256 + nn];
}

__global__ __launch_bounds__(256) void pkn_ln(const float* __restrict__ pe_k,
                                              const float* __restrict__ lnk_g,
                                              const float* __restrict__ lnk_b,
                                              bf16_t* __restrict__ out) {
  const int idx = blockIdx.x * 4 + (threadIdx.x >> 6);
  if (idx >= L_ * PKROWS) return;
  const int lane = threadIdx.x & 63;
  const int l = idx / PKROWS, r = idx - l * PKROWS;
  float v = pe_k[(size_t)r * DK + lane];
  float s = v;
#pragma unroll
  for (int o = 32; o; o >>= 1) s += __shfl_xor(s, o);
  const float mean = s * (1.f / DK);
  const float dx = v - mean;
  float q = dx * dx;
#pragma unroll
  for (int o = 32; o; o >>= 1) q += __shfl_xor(q, o);
  const float rs = rsqrtf(q * (1.f / DK) + 1e-12f);
  out[((size_t)l * PKROWS + r) * DK + lane] =
      (bf16_t)(dx * rs * lnk_g[l * DK + lane] + lnk_b[l * DK + lane]);
}

// ---------------------------------------------------------------------------
// LayerNorm over rows of 256 (one wave per row)
// ---------------------------------------------------------------------------
template <bool BF16OUT, bool RELU>
__global__ __launch_bounds__(256) void ln_rows(const float* __restrict__ src,
                                               const float* __restrict__ g,
                                               const float* __restrict__ b,
                                               void* __restrict__ dst) {
  const int row = blockIdx.x * 4 + (threadIdx.x >> 6);
  const int lane = threadIdx.x & 63;
  const float4 v = ((const float4*)(src + (size_t)row * D_))[lane];
  float s = v.x + v.y + v.z + v.w;
#pragma unroll
  for (int o = 32; o; o >>= 1) s += __shfl_xor(s, o);
  const float mean = s * (1.f / D_);
  const float d0 = v.x - mean, d1 = v.y - mean, d2 = v.z - mean, d3 = v.w - mean;
  float q = d0 * d0 + d1 * d1 + d2 * d2 + d3 * d3;
#pragma unroll
  for (int o = 32; o; o >>= 1) q += __shfl_xor(q, o);
  const float rs = rsqrtf(q * (1.f / D_) + 1e-12f);
  const float4 gg = ((const float4*)g)[lane];
  const float4 bb = ((const float4*)b)[lane];
  float o0 = d0 * rs * gg.x + bb.x;
  float o1 = d1 * rs * gg.y + bb.y;
  float o2 = d2 * rs * gg.z + bb.z;
  float o3 = d3 * rs * gg.w + bb.w;
  if (RELU) {
    o0 = fmaxf(o0, 0.f); o1 = fmaxf(o1, 0.f);
    o2 = fmaxf(o2, 0.f); o3 = fmaxf(o3, 0.f);
  }
  if (BF16OUT) {
    bf16x4 o4 = {(bf16_t)o0, (bf16_t)o1, (bf16_t)o2, (bf16_t)o3};
    ((bf16x4*)((bf16_t*)dst + (size_t)row * D_))[lane] = o4;
  } else {
    ((float4*)((float*)dst + (size_t)row * D_))[lane] = make_float4(o0, o1, o2, o3);
  }
}

// ---------------------------------------------------------------------------
// combine for split-K GEMM partials: x = x + sum(parts) + bias; y = LN(x)
// ---------------------------------------------------------------------------
template <int NS, bool WRITE_Y>
__global__ __launch_bounds__(256) void add_combine_ln(
    const float* __restrict__ parts, const float* __restrict__ bias,
    float* __restrict__ x, const float* __restrict__ g,
    const float* __restrict__ b, bf16_t* __restrict__ y) {
  const int row = blockIdx.x * 4 + (threadIdx.x >> 6);
  const int lane = threadIdx.x & 63;
  const size_t idx = (size_t)row * 64 + lane;
  float4 v = ((const float4*)x)[idx];
#pragma unroll
  for (int p = 0; p < NS; ++p) {
    float4 pv = ((const float4*)parts)[(size_t)p * NROW * 64 + idx];
    v.x += pv.x; v.y += pv.y; v.z += pv.z; v.w += pv.w;
  }
  const float4 bi = ((const float4*)bias)[lane];
  v.x += bi.x; v.y += bi.y; v.z += bi.z; v.w += bi.w;
  ((float4*)x)[idx] = v;
  if (WRITE_Y) {
    float s = v.x + v.y + v.z + v.w;
#pragma unroll
    for (int o = 32; o; o >>= 1) s += __shfl_xor(s, o);
    const float mean = s * (1.f / D_);
    const float d0 = v.x - mean, d1 = v.y - mean, d2 = v.z - mean, d3 = v.w - mean;
    float q = d0 * d0 + d1 * d1 + d2 * d2 + d3 * d3;
#pragma unroll
    for (int o = 32; o; o >>= 1) q += __shfl_xor(q, o);
    const float rs = rsqrtf(q * (1.f / D_) + 1e-12f);
    const float4 gg = ((const float4*)g)[lane];
    const float4 bb = ((const float4*)b)[lane];
    bf16x4 o4 = {(bf16_t)(d0 * rs * gg.x + bb.x), (bf16_t)(d1 * rs * gg.y + bb.y),
                 (bf16_t)(d2 * rs * gg.z + bb.z), (bf16_t)(d3 * rs * gg.w + bb.w)};
    ((bf16x4*)y)[idx] = o4;
  }
}

// embed combine: x = relu(LN(sum(parts)+bias))
__global__ __launch_bounds__(256) void embed_combine(
    const float* __restrict__ parts, const float* __restrict__ bias,
    const float* __restrict__ g, const float* __restrict__ b,
    float* __restrict__ x) {
  const int row = blockIdx.x * 4 + (threadIdx.x >> 6);
  const int lane = threadIdx.x & 63;
  const size_t idx = (size_t)row * 64 + lane;
  float4 v = ((const float4*)parts)[idx];
  float4 p1 = ((const float4*)parts)[(size_t)NROW * 64 + idx];
  const float4 bi = ((const float4*)bias)[lane];
  v.x += p1.x + bi.x; v.y += p1.y + bi.y; v.z += p1.z + bi.z; v.w += p1.w + bi.w;
  float s = v.x + v.y + v.z + v.w;
#pragma unroll
  for (int o = 32; o; o >>= 1) s += __shfl_xor(s, o);
  const float mean = s * (1.f / D_);
  const float d0 = v.x - mean, d1 = v.y - mean, d2 = v.z - mean, d3 = v.w - mean;
  float q = d0 * d0 + d1 * d1 + d2 * d2 + d3 * d3;
#pragma unroll
  for (int o = 32; o; o >>= 1) q += __shfl_xor(q, o);
  const float rs = rsqrtf(q * (1.f / D_) + 1e-12f);
  const float4 gg = ((const float4*)g)[lane];
  const float4 bb = ((const float4*)b)[lane];
  ((float4*)x)[idx] = make_float4(
      fmaxf(d0 * rs * gg.x + bb.x, 0.f), fmaxf(d1 * rs * gg.y + bb.y, 0.f),
      fmaxf(d2 * rs * gg.z + bb.z, 0.f), fmaxf(d3 * rs * gg.w + bb.w, 0.f));
}

// ---------------------------------------------------------------------------
// bf16 NT GEMM, BK=64: C[M,N] = A[M,K] * B[N,K]^T, split-K via blockIdx.z.
// Staging: async 16B chunks, physical layout tid-linear; logical k-chunk at
// physical slot c8 is c8^(r&7) (conflict-floor ds_read_b128).
// EP: 0 f32 bias; 1 bf16 bias; 2 bf16 bias+relu; 3 f32 bias+resid;
//     4 f32 raw partial at Cout + z*zstride
// ---------------------------------------------------------------------------
template <int BM, int BN, int EP, int MINW>
__global__ __launch_bounds__(256, MINW) void gemm_bf16(
    const bf16_t* __restrict__ A, int lda, const bf16_t* __restrict__ B, int ldb,
    const float* __restrict__ bias, void* __restrict__ Cout, int ldc,
    const float* __restrict__ resid, int K, size_t zstride) {
  constexpr int HM = BM / 2, HN = BN / 2;
  constexpr int FM = HM / 16, FN = HN / 16;
  constexpr int CA = (BM * 8) / 256, CB = (BN * 8) / 256;
  __shared__ bf16_t lsA[BM * 64];
  __shared__ bf16_t lsB[BN * 64];
  const int tid = threadIdx.x;
  const int w = tid >> 6, lane = tid & 63;
  const int wm = w >> 1, wn = w & 1;
  const int lanelo = lane & 15, quad = lane >> 4;
  const int wbase = tid & ~63;
  const int m0 = blockIdx.x * BM, n0 = blockIdx.y * BN;
  const int ktiles = K >> 6;
  const int tpz = (ktiles + gridDim.z - 1) / gridDim.z;
  const int kb = blockIdx.z * tpz * 64;
  const int ke = min(K, kb + tpz * 64);
  f32x4 acc[FM][FN] = {};

  for (int kt = kb; kt < ke; kt += 64) {
    __syncthreads();
#pragma unroll
    for (int rr = 0; rr < CA; ++rr) {
      int chunk = rr * 256 + tid;
      int r = chunk >> 3, c8 = chunk & 7;
      int lg = c8 ^ (r & 7);
      async_cp16(A + (size_t)(m0 + r) * lda + kt + lg * 8,
                 lsA + (size_t)(rr * 256 + wbase) * 8);
    }
#pragma unroll
    for (int rr = 0; rr < CB; ++rr) {
      int chunk = rr * 256 + tid;
      int r = chunk >> 3, c8 = chunk & 7;
      int lg = c8 ^ (r & 7);
      async_cp16(B + (size_t)(n0 + r) * ldb + kt + lg * 8,
                 lsB + (size_t)(rr * 256 + wbase) * 8);
    }
    __syncthreads();
    bf16x8 af[FM][2], bfv[FN][2];
#pragma unroll
    for (int i = 0; i < FM; ++i) {
      int r = wm * HM + i * 16 + lanelo;
#pragma unroll
      for (int kk = 0; kk < 2; ++kk)
        af[i][kk] = *(const bf16x8*)(lsA + (size_t)(r * 8 + ((kk * 4 + quad) ^ (r & 7))) * 8);
    }
#pragma unroll
    for (int j = 0; j < FN; ++j) {
      int r = wn * HN + j * 16 + lanelo;
#pragma unroll
      for (int kk = 0; kk < 2; ++kk)
        bfv[j][kk] = *(const bf16x8*)(lsB + (size_t)(r * 8 + ((kk * 4 + quad) ^ (r & 7))) * 8);
    }
#pragma unroll
    for (int kk = 0; kk < 2; ++kk)
#pragma unroll
      for (int i = 0; i < FM; ++i)
#pragma unroll
        for (int j = 0; j < FN; ++j)
          acc[i][j] = mfma16(af[i][kk], bfv[j][kk], acc[i][j]);
  }

#pragma unroll
  for (int i = 0; i < FM; ++i) {
#pragma unroll
    for (int j = 0; j < FN; ++j) {
#pragma unroll
      for (int reg = 0; reg < 4; ++reg) {
        const int m = m0 + wm * HM + i * 16 + quad * 4 + reg;
        const int n = n0 + wn * HN + j * 16 + lanelo;
        const size_t idx = (size_t)m * ldc + n;
        if constexpr (EP == 4) {
          ((float*)Cout + (size_t)blockIdx.z * zstride)[idx] = acc[i][j][reg];
        } else {
          float v = acc[i][j][reg] + bias[n];
          if constexpr (EP == 0) {
            ((float*)Cout)[idx] = v;
          } else if constexpr (EP == 1) {
            ((bf16_t*)Cout)[idx] = (bf16_t)v;
          } else if constexpr (EP == 2) {
            ((bf16_t*)Cout)[idx] = (bf16_t)fmaxf(v, 0.f);
          } else {
            ((float*)Cout)[idx] = v + resid[idx];
          }
        }
      }
    }
  }
}

// ---------------------------------------------------------------------------
// bt_gemm: Bt[bh][t][s] = q[bh,t] . pkn[t-s+1000]  (bf16 out)
// grid (T/64, NBH). Per block: R[64 x 576] over 3 chunks of 192 j-cols.
// ---------------------------------------------------------------------------
__global__ __launch_bounds__(256, 3) void bt_gemm(
    const bf16_t* __restrict__ qkv, const bf16_t* __restrict__ pkn,
    bf16_t* __restrict__ Bt) {
  __shared__ bf16_t ls_q[64 * 64];    // 8 KB, swizzled
  __shared__ bf16_t ls_j[192 * 64];   // 24 KB, swizzled
  const int tid = threadIdx.x, w = tid >> 6, lane = tid & 63;
  const int wm = w >> 1, wn = w & 1;
  const int lanelo = lane & 15, quad = lane >> 4;
  const int wbase = tid & ~63;
  const int t0 = blockIdx.x * 64;
  const int bh = blockIdx.y, bb = bh >> 2, h = bh & 3;
  const size_t rowbase = (size_t)bb * T_;
  const int relbase = t0 + 489;

  // stage q (rows t0..t0+64, head h)
#pragma unroll
  for (int rr = 0; rr < 2; ++rr) {
    int chunk = rr * 256 + tid;
    int r = chunk >> 3, c8 = chunk & 7;
    int lg = c8 ^ (r & 7);
    async_cp16(qkv + (rowbase + t0 + r) * 768 + h * 64 + lg * 8,
               ls_q + (size_t)(rr * 256 + wbase) * 8);
  }
  __syncthreads();
  bf16x8 qf[2][2];
#pragma unroll
  for (int i = 0; i < 2; ++i) {
    int r = wm * 32 + i * 16 + lanelo;
#pragma unroll
    for (int kk = 0; kk < 2; ++kk)
      qf[i][kk] = *(const bf16x8*)(ls_q + (size_t)(r * 8 + ((kk * 4 + quad) ^ (r & 7))) * 8);
  }

  for (int jc = 0; jc < 3; ++jc) {
    if (jc) __syncthreads();
#pragma unroll
    for (int rr = 0; rr < 6; ++rr) {
      int chunk = rr * 256 + tid;
      int r = chunk >> 3, c8 = chunk & 7;
      int lg = c8 ^ (r & 7);
      async_cp16(pkn + (size_t)(relbase + jc * 192 + r) * DK + lg * 8,
                 ls_j + (size_t)(rr * 256 + wbase) * 8);
    }
    __syncthreads();
    f32x4 racc[2][6] = {};
#pragma unroll
    for (int kk = 0; kk < 2; ++kk)
#pragma unroll
      for (int nf = 0; nf < 6; ++nf) {
        int r = wn * 96 + nf * 16 + lanelo;
        bf16x8 bj = *(const bf16x8*)(ls_j + (size_t)(r * 8 + ((kk * 4 + quad) ^ (r & 7))) * 8);
#pragma unroll
        for (int i = 0; i < 2; ++i) racc[i][nf] = mfma16(qf[i][kk], bj, racc[i][nf]);
      }
    // scatter to Bt: s = (t - t0) + 511 - jj
#pragma unroll
    for (int i = 0; i < 2; ++i)
#pragma unroll
      for (int nf = 0; nf < 6; ++nf)
#pragma unroll
        for (int reg = 0; reg < 4; ++reg) {
          const int tl = wm * 32 + i * 16 + quad * 4 + reg;  // t - t0
          const int jj = jc * 192 + wn * 96 + nf * 16 + lanelo;
          const int s = tl + 511 - jj;
          if (s >= 0 && s < T_)
            Bt[(((size_t)bh * T_ + t0 + tl) << 9) + s] = (bf16_t)racc[i][nf][reg];
        }
  }
}

// ---------------------------------------------------------------------------
// Flash attention partial: grid (T/64, NBH, NSA); 2 s-tiles per block.
// LDS 34.8 KB -> 4 blocks/CU; 2 barriers per s-tile.
// ---------------------------------------------------------------------------
__global__ __launch_bounds__(256, 4) void attn_part(
    const bf16_t* __restrict__ qkv, const bf16_t* __restrict__ Bt,
    const int* __restrict__ masks, bf16_t* __restrict__ Opart,
    float* __restrict__ mpart, float* __restrict__ lpart) {
  __shared__ bf16_t ls_q[64 * 64];   // 8 KB, swizzled
  __shared__ bf16_t ls_k[64 * 64];   // 8 KB, swizzled
  __shared__ bf16_t ls_vt[64 * 72];  // 9.2 KB [d][s], padded
  __shared__ bf16_t ls_p[64 * 72];   // 9.2 KB, padded

  const int tid = threadIdx.x, w = tid >> 6, lane = tid & 63;
  const int lanelo = lane & 15, quad = lane >> 4;
  const int wbase = tid & ~63;
  const int t0 = blockIdx.x * 64;
  const int bh = blockIdx.y, bb = bh >> 2, h = bh & 3;
  const int z = blockIdx.z;
  const size_t rowbase = (size_t)bb * T_;

  // stage q once (async, swizzled)
#pragma unroll
  for (int rr = 0; rr < 2; ++rr) {
    int chunk = rr * 256 + tid;
    int r = chunk >> 3, c8 = chunk & 7;
    int lg = c8 ^ (r & 7);
    async_cp16(qkv + (rowbase + t0 + r) * 768 + h * 64 + lg * 8,
               ls_q + (size_t)(rr * 256 + wbase) * 8);
  }
  __syncthreads();
  bf16x8 qf[2];
#pragma unroll
  for (int kk = 0; kk < 2; ++kk) {
    int r = w * 16 + lanelo;
    qf[kk] = *(const bf16x8*)(ls_q + (size_t)(r * 8 + ((kk * 4 + quad) ^ (r & 7))) * 8);
  }

  f32x4 o_acc[4] = {};
  float m_run[4], l_run[4];
#pragma unroll
  for (int i = 0; i < 4; ++i) { m_run[i] = -__builtin_inff(); l_run[i] = 0.f; }

  for (int st = 2 * z; st < 2 * z + 2; ++st) {
    const int s0 = st * 64;
    __syncthreads();  // prev-tile LDS reads complete
    // stage K (async, swizzled)
#pragma unroll
    for (int rr = 0; rr < 2; ++rr) {
      int chunk = rr * 256 + tid;
      int r = chunk >> 3, c8 = chunk & 7;
      int lg = c8 ^ (r & 7);
      async_cp16(qkv + (rowbase + s0 + r) * 768 + 256 + h * 64 + lg * 8,
                 ls_k + (size_t)(rr * 256 + wbase) * 8);
    }
    // stage V^T [d][s]: lanes walk s -> conflict-free LDS writes
#pragma unroll
    for (int c = tid; c < 64 * 8; c += 256) {
      int r = c & 63, d0 = (c >> 6) * 8;
      bf16x8 vv = *(const bf16x8*)(qkv + (rowbase + s0 + r) * 768 + 512 + h * 64 + d0);
#pragma unroll
      for (int i = 0; i < 8; ++i) ls_vt[(d0 + i) * 72 + r] = vv[i];
    }
    __syncthreads();

    // preload mask + bias tile (VMEM latency hidden behind S GEMM)
    float btv[4][4];
    int mk[4];
#pragma unroll
    for (int nf = 0; nf < 4; ++nf) {
      const int scol = nf * 16 + lanelo;
      mk[nf] = masks[bb * T_ + s0 + scol];
#pragma unroll
      for (int reg = 0; reg < 4; ++reg) {
        const int trow = w * 16 + quad * 4 + reg;
        btv[nf][reg] = (float)Bt[(((size_t)bh * T_ + t0 + trow) << 9) + s0 + scol];
      }
    }
    // S GEMM
    f32x4 sacc[4] = {};
#pragma unroll
    for (int kk = 0; kk < 2; ++kk)
#pragma unroll
      for (int nf = 0; nf < 4; ++nf) {
        int r = nf * 16 + lanelo;
        bf16x8 bk = *(const bf16x8*)(ls_k + (size_t)(r * 8 + ((kk * 4 + quad) ^ (r & 7))) * 8);
        sacc[nf] = mfma16(qf[kk], bk, sacc[nf]);
      }
    // scores
    float sv[4][4];
#pragma unroll
    for (int nf = 0; nf < 4; ++nf)
#pragma unroll
      for (int reg = 0; reg < 4; ++reg)
        sv[nf][reg] = mk[nf] ? (sacc[nf][reg] + btv[nf][reg]) * 0.125f
                             : -3.4028235e38f;
    // online softmax
    float alpha[4];
#pragma unroll
    for (int reg = 0; reg < 4; ++reg) {
      float bm = fmaxf(fmaxf(sv[0][reg], sv[1][reg]), fmaxf(sv[2][reg], sv[3][reg]));
#pragma unroll
      for (int o = 1; o < 16; o <<= 1) bm = fmaxf(bm, __shfl_xor(bm, o));
      const float mn = fmaxf(m_run[reg], bm);
      alpha[reg] = __expf(m_run[reg] - mn);
      m_run[reg] = mn;
      float rsum = 0.f;
#pragma unroll
      for (int nf = 0; nf < 4; ++nf) {
        float p = __expf(sv[nf][reg] - mn) * (mk[nf] ? 1.f : 0.f);
        sv[nf][reg] = p;
        rsum += p;
      }
#pragma unroll
      for (int o = 1; o < 16; o <<= 1) rsum += __shfl_xor(rsum, o);
      l_run[reg] = l_run[reg] * alpha[reg] + rsum;
    }
    // P write (same-wave rows) + PV
#pragma unroll
    for (int nf = 0; nf < 4; ++nf)
#pragma unroll
      for (int reg = 0; reg < 4; ++reg) {
        o_acc[nf][reg] *= alpha[reg];
        ls_p[(w * 16 + quad * 4 + reg) * 72 + nf * 16 + lanelo] = (bf16_t)sv[nf][reg];
      }
#pragma unroll
    for (int kk = 0; kk < 2; ++kk) {
      bf16x8 ap = *(const bf16x8*)&ls_p[(w * 16 + lanelo) * 72 + kk * 32 + quad * 8];
#pragma unroll
      for (int nf = 0; nf < 4; ++nf) {
        bf16x8 bv = *(const bf16x8*)&ls_vt[(nf * 16 + lanelo) * 72 + kk * 32 + quad * 8];
        o_acc[nf] = mfma16(ap, bv, o_acc[nf]);
      }
    }
  }

  // write split partials (bf16 O)
#pragma unroll
  for (int reg = 0; reg < 4; ++reg) {
    const int trow = w * 16 + quad * 4 + reg;
    const size_t prow = ((size_t)z * NBH + bh) * T_ + t0 + trow;
#pragma unroll
    for (int nf = 0; nf < 4; ++nf)
      Opart[prow * 64 + nf * 16 + lanelo] = (bf16_t)o_acc[nf][reg];
    if (lanelo == 0) { mpart[prow] = m_run[reg]; lpart[prow] = l_run[reg]; }
  }
}

// combine attention splits -> ao bf16 [4096,256]
__global__ __launch_bounds__(256) void attn_combine(
    const bf16_t* __restrict__ Opart, const float* __restrict__ mpart,
    const float* __restrict__ lpart, bf16_t* __restrict__ ao) {
  const int hr = blockIdx.x * 4 + (threadIdx.x >> 6);  // 0..NBH*T-1
  const int lane = threadIdx.x & 63;
  const int bh = hr >> 9, t = hr & 511;
  float mp[NSA], lp[NSA];
  float m = -__builtin_inff();
#pragma unroll
  for (int p = 0; p < NSA; ++p) {
    const size_t prow = ((size_t)p * NBH + bh) * T_ + t;
    mp[p] = mpart[prow]; lp[p] = lpart[prow];
    m = fmaxf(m, mp[p]);
  }
  float denom = 0.f, o = 0.f;
#pragma unroll
  for (int p = 0; p < NSA; ++p) {
    if (lp[p] > 0.f) {
      const float wp = __expf(mp[p] - m);
      denom += lp[p] * wp;
      o += (float)Opart[(((size_t)p * NBH + bh) * T_ + t) * 64 + lane] * wp;
    }
  }
  const float res = (denom > 0.f) ? o / denom : 0.f;
  const int bb = bh >> 2, hh = bh & 3;
  ao[((size_t)bb * T_ + t) * D_ + hh * 64 + lane] = (bf16_t)res;
}

// ---------------------------------------------------------------------------
// host
// ---------------------------------------------------------------------------
extern "C" void kernel_launch(void* const* d_in, const int* in_sizes, int n_in,
                              void* d_out, int out_size, void* d_ws, size_t ws_size,
                              hipStream_t stream) {
  const float* xs       = (const float*)d_in[0];
  const int*   masks    = (const int*)d_in[1];
  const float* emb_w    = (const float*)d_in[2];
  const float* emb_b    = (const float*)d_in[3];
  const float* emb_g    = (const float*)d_in[4];
  const float* emb_beta = (const float*)d_in[5];
  const float* pe_k     = (const float*)d_in[6];
  const float* Wq       = (const float*)d_in[7];
  const float* bq       = (const float*)d_in[8];
  const float* Wk       = (const float*)d_in[9];
  const float* bk       = (const float*)d_in[10];
  const float* Wv       = (const float*)d_in[11];
  const float* bv       = (const float*)d_in[12];
  const float* Wo       = (const float*)d_in[13];
  const float* bo       = (const float*)d_in[14];
  const float* ln1_g    = (const float*)d_in[15];
  const float* ln1_b    = (const float*)d_in[16];
  const float* ln2_g    = (const float*)d_in[17];
  const float* ln2_b    = (const float*)d_in[18];
  const float* lnk_g    = (const float*)d_in[19];
  const float* lnk_b    = (const float*)d_in[20];
  const float* W1       = (const float*)d_in[21];
  const float* b1       = (const float*)d_in[22];
  const float* W2       = (const float*)d_in[23];
  const float* b2       = (const float*)d_in[24];
  const float* after_g  = (const float*)d_in[25];
  const float* after_b  = (const float*)d_in[26];

  char* ws = (char*)d_ws;
  size_t off = 0;
  auto take = [&](size_t bytes) -> void* {
    void* p = ws + off;
    off += (bytes + 255) & ~(size_t)255;
    return p;
  };
  bf16_t* ewb  = (bf16_t*)take((size_t)D_ * KPAD * 2);
  bf16_t* wcat = (bf16_t*)take((size_t)L_ * 768 * D_ * 2);
  float*  bcat = (float*) take((size_t)L_ * 768 * 4);
  bf16_t* wob  = (bf16_t*)take((size_t)L_ * D_ * D_ * 2);
  bf16_t* w1b  = (bf16_t*)take((size_t)L_ * FF_ * D_ * 2);
  bf16_t* w2b  = (bf16_t*)take((size_t)L_ * D_ * FF_ * 2);
  bf16_t* pknb = (bf16_t*)take((size_t)L_ * PKROWS * DK * 2);
  float*  x    = (float*) take((size_t)NROW * D_ * 4);
  bf16_t* y    = (bf16_t*)take((size_t)NROW * D_ * 2);
  bf16_t* qkv  = (bf16_t*)take((size_t)NROW * 768 * 2);
  bf16_t* ao   = (bf16_t*)take((size_t)NROW * D_ * 2);
  bf16_t* hbuf = (bf16_t*)take((size_t)NROW * FF_ * 2);
  bf16_t* Btb  = (bf16_t*)take((size_t)NBH * T_ * T_ * 2);           // 16.8 MB
  bf16_t* Opart = (bf16_t*)take((size_t)NSA * NBH * T_ * 64 * 2);    // 8.4 MB
  float*  mpart = (float*)take((size_t)NSA * NBH * T_ * 4);
  float*  lpart = (float*)take((size_t)NSA * NBH * T_ * 4);
  float*  gpart = (float*)take((size_t)2 * NROW * D_ * 4);           // 8 MB
  bf16_t* xsb  = hbuf;          // xs bf16 (15.2MB) only needed before first FF1
  const size_t ZS = (size_t)NROW * D_;

  // prep
  cvt_pad_row<<<NROW, 256, 0, stream>>>(xs, xsb, IDIM, KPAD);
  cvt_pad_row<<<D_, 256, 0, stream>>>(emb_w, ewb, IDIM, KPAD);
  pack_qkvw<<<2048, 256, 0, stream>>>(Wq, Wk, Wv, wcat);
  pack_qkvb<<<48, 256, 0, stream>>>(bq, bk, bv, bcat);
  cvt_f32_bf16<<<1024, 256, 0, stream>>>(Wo, wob, L_ * D_ * D_);
  cvt_f32_bf16<<<2048, 256, 0, stream>>>(W1, w1b, L_ * FF_ * D_);
  cvt_f32_bf16<<<2048, 256, 0, stream>>>(W2, w2b, L_ * D_ * FF_);
  pkn_ln<<<(L_ * PKROWS) / 4, 256, 0, stream>>>(pe_k, lnk_g, lnk_b, pknb);

  // embed: split-K=2 GEMM -> combine(LN+relu) -> x; then ln1 layer0 -> y
  gemm_bf16<64, 64, 4, 3><<<dim3(NROW / 64, D_ / 64, 2), 256, 0, stream>>>(
      xsb, KPAD, ewb, KPAD, nullptr, gpart, D_, nullptr, KPAD, ZS);
  embed_combine<<<NROW / 4, 256, 0, stream>>>(gpart, emb_b, emb_g, emb_beta, x);
  ln_rows<true, false><<<NROW / 4, 256, 0, stream>>>(x, ln1_g, ln1_b, y);

  for (int l = 0; l < L_; ++l) {
    gemm_bf16<64, 64, 1, 3><<<dim3(NROW / 64, 768 / 64), 256, 0, stream>>>(
        y, D_, wcat + (size_t)l * 768 * D_, D_, bcat + l * 768, qkv, 768, nullptr,
        D_, 0);
    bt_gemm<<<dim3(T_ / 64, NBH), 256, 0, stream>>>(
        qkv, pknb + (size_t)l * PKROWS * DK, Btb);
    attn_part<<<dim3(T_ / 64, NBH, NSA), 256, 0, stream>>>(
        qkv, Btb, masks, Opart, mpart, lpart);
    attn_combine<<<NBH * T_ / 4, 256, 0, stream>>>(Opart, mpart, lpart, ao);
    gemm_bf16<64, 64, 4, 3><<<dim3(NROW / 64, D_ / 64, 2), 256, 0, stream>>>(
        ao, D_, wob + (size_t)l * D_ * D_, D_, nullptr, gpart, D_, nullptr, D_, ZS);
    add_combine_ln<2, true><<<NROW / 4, 256, 0, stream>>>(
        gpart, bo + l * D_, x, ln2_g + l * D_, ln2_b + l * D_, y);
    gemm_bf16<128, 128, 2, 2><<<dim3(NROW / 128, FF_ / 128), 256, 0, stream>>>(
        y, D_, w1b + (size_t)l * FF_ * D_, D_, b1 + l * FF_, hbuf, FF_, nullptr,
        D_, 0);
    gemm_bf16<64, 64, 4, 3><<<dim3(NROW / 64, D_ / 64, 2), 256, 0, stream>>>(
        hbuf, FF_, w2b + (size_t)l * D_ * FF_, FF_, nullptr, gpart, D_, nullptr,
        FF_, ZS);
    if (l < L_ - 1) {
      add_combine_ln<2, true><<<NROW / 4, 256, 0, stream>>>(
          gpart, b2 + l * D_, x, ln1_g + (l + 1) * D_, ln1_b + (l + 1) * D_, y);
    } else {
      add_combine_ln<2, false><<<NROW / 4, 256, 0, stream>>>(
          gpart, b2 + l * D_, x, nullptr, nullptr, nullptr);
    }
  }
  ln_rows<false, false><<<NROW / 4, 256, 0, stream>>>(x, after_g, after_b,
                                                      (float*)d_out);
}

// Round 4
// 1332.608 us; speedup vs baseline: 1.2789x; 1.0776x over previous
//
#include <hip/hip_runtime.h>
#include <cstdint>

// ---------------------------------------------------------------------------
// EETransformerEncoder on MI355X (gfx950).  Round 4.
// - attention: rel-pos R computed ONCE per block into LDS (no Bt HBM traffic,
//   no bt_gemm dispatch); flash loop 2 barriers/s-tile; 3 blocks/CU.
// - Wo GEMM stages A by combining the 4 attention splits inline (attn_combine
//   dispatch and ao buffer removed).
// - FF2/embed: 128x128 tiles split-K=4 (halved A re-read); QKV BN=128.
// ---------------------------------------------------------------------------

typedef __bf16 bf16_t;
typedef bf16_t bf16x4 __attribute__((ext_vector_type(4)));
typedef bf16_t bf16x8 __attribute__((ext_vector_type(8)));
typedef float  f32x4  __attribute__((ext_vector_type(4)));

#define B_    8
#define T_    512
#define IDIM  1799
#define KPAD  1856        // 29*64
#define D_    256
#define H_    4
#define DK    64
#define FF_   2048
#define L_    16
#define NROW  4096        // B_*T_
#define PKROWS 2000       // 2*MAXLEN
#define NBH   32          // B_*H_
#define NSA   4           // attention s-splits

__device__ __forceinline__ f32x4 mfma16(bf16x8 a, bf16x8 b, f32x4 c) {
  return __builtin_amdgcn_mfma_f32_16x16x32_bf16(a, b, c, 0, 0, 0);
}

__device__ __forceinline__ void async_cp16(const void* g, void* l) {
  __builtin_amdgcn_global_load_lds(
      (__attribute__((address_space(1))) void*)(g),
      (__attribute__((address_space(3))) void*)(l), 16, 0, 0);
}

// ---------------------------------------------------------------------------
// conversions / packing
// ---------------------------------------------------------------------------
__global__ __launch_bounds__(256) void cvt_f32_bf16(const float* __restrict__ s,
                                                    bf16_t* __restrict__ d, int n) {
  int i = blockIdx.x * 256 + threadIdx.x;
  int stride = gridDim.x * 256;
  for (; i < n; i += stride) d[i] = (bf16_t)s[i];
}

__global__ __launch_bounds__(256) void cvt_pad_row(const float* __restrict__ s,
                                                   bf16_t* __restrict__ d,
                                                   int ksrc, int kdst) {
  const int r = blockIdx.x;
  const float* sr = s + (size_t)r * ksrc;
  bf16_t* dr = d + (size_t)r * kdst;
  for (int k = threadIdx.x; k < kdst; k += 256)
    dr[k] = (k < ksrc) ? (bf16_t)sr[k] : (bf16_t)0.f;
}

__global__ __launch_bounds__(256) void pack_qkvw(const float* __restrict__ wq,
                                                 const float* __restrict__ wk,
                                                 const float* __restrict__ wv,
                                                 bf16_t* __restrict__ dst) {
  const int per_l = 768 * 256;
  int i = blockIdx.x * 256 + threadIdx.x;
  int stride = gridDim.x * 256;
  for (; i < L_ * per_l; i += stride) {
    int l = i / per_l, r = i - l * per_l;
    int n = r >> 8, c = r & 255;
    int sel = n >> 8, nn = n & 255;
    const float* w = (sel == 0) ? wq : (sel == 1) ? wk : wv;
    dst[i] = (bf16_t)w[((size_t)l * 256 + nn) * 256 + c];
  }
}

__global__ __launch_bounds__(256) void pack_qkvb(const float* __restrict__ bq,
                                                 const float* __restrict__ bk,
                                                 const float* __restrict__ bv,
                                                 float* __restrict__ dst) {
  int i = blockIdx.x * 256 + threadIdx.x;
  if (i >= L_ * 768) return;
  int l = i / 768, n = i - l * 768;
  int sel = n >> 8, nn = n & 255;
  const float* b = (sel == 0) ? bq : (sel == 1) ? bk : bv;
  dst[i] = b[l * 256 + nn];
}

__global__ __launch_bounds__(256) void pkn_ln(const float* __restrict__ pe_k,
                                              const float* __restrict__ lnk_g,
                                              const float* __restrict__ lnk_b,
                                              bf16_t* __restrict__ out) {
  const int idx = blockIdx.x * 4 + (threadIdx.x >> 6);
  if (idx >= L_ * PKROWS) return;
  const int lane = threadIdx.x & 63;
  const int l = idx / PKROWS, r = idx - l * PKROWS;
  float v = pe_k[(size_t)r * DK + lane];
  float s = v;
#pragma unroll
  for (int o = 32; o; o >>= 1) s += __shfl_xor(s, o);
  const float mean = s * (1.f / DK);
  const float dx = v - mean;
  float q = dx * dx;
#pragma unroll
  for (int o = 32; o; o >>= 1) q += __shfl_xor(q, o);
  const float rs = rsqrtf(q * (1.f / DK) + 1e-12f);
  out[((size_t)l * PKROWS + r) * DK + lane] =
      (bf16_t)(dx * rs * lnk_g[l * DK + lane] + lnk_b[l * DK + lane]);
}

// ---------------------------------------------------------------------------
// final LayerNorm over rows of 256 (one wave per row)
// ---------------------------------------------------------------------------
__global__ __launch_bounds__(256) void ln_rows_f32(const float* __restrict__ src,
                                                   const float* __restrict__ g,
                                                   const float* __restrict__ b,
                                                   float* __restrict__ dst) {
  const int row = blockIdx.x * 4 + (threadIdx.x >> 6);
  const int lane = threadIdx.x & 63;
  const float4 v = ((const float4*)(src + (size_t)row * D_))[lane];
  float s = v.x + v.y + v.z + v.w;
#pragma unroll
  for (int o = 32; o; o >>= 1) s += __shfl_xor(s, o);
  const float mean = s * (1.f / D_);
  const float d0 = v.x - mean, d1 = v.y - mean, d2 = v.z - mean, d3 = v.w - mean;
  float q = d0 * d0 + d1 * d1 + d2 * d2 + d3 * d3;
#pragma unroll
  for (int o = 32; o; o >>= 1) q += __shfl_xor(q, o);
  const float rs = rsqrtf(q * (1.f / D_) + 1e-12f);
  const float4 gg = ((const float4*)g)[lane];
  const float4 bb = ((const float4*)b)[lane];
  ((float4*)(dst + (size_t)row * D_))[lane] =
      make_float4(d0 * rs * gg.x + bb.x, d1 * rs * gg.y + bb.y,
                  d2 * rs * gg.z + bb.z, d3 * rs * gg.w + bb.w);
}

// ---------------------------------------------------------------------------
// combine split-K GEMM partials: x += sum(parts)+bias; optionally y = LN(x)
// ---------------------------------------------------------------------------
template <int NS, bool WRITE_Y>
__global__ __launch_bounds__(256) void add_combine_ln(
    const float* __restrict__ parts, const float* __restrict__ bias,
    float* __restrict__ x, const float* __restrict__ g,
    const float* __restrict__ b, bf16_t* __restrict__ y) {
  const int row = blockIdx.x * 4 + (threadIdx.x >> 6);
  const int lane = threadIdx.x & 63;
  const size_t idx = (size_t)row * 64 + lane;
  float4 v = ((const float4*)x)[idx];
#pragma unroll
  for (int p = 0; p < NS; ++p) {
    float4 pv = ((const float4*)parts)[(size_t)p * NROW * 64 + idx];
    v.x += pv.x; v.y += pv.y; v.z += pv.z; v.w += pv.w;
  }
  const float4 bi = ((const float4*)bias)[lane];
  v.x += bi.x; v.y += bi.y; v.z += bi.z; v.w += bi.w;
  ((float4*)x)[idx] = v;
  if (WRITE_Y) {
    float s = v.x + v.y + v.z + v.w;
#pragma unroll
    for (int o = 32; o; o >>= 1) s += __shfl_xor(s, o);
    const float mean = s * (1.f / D_);
    const float d0 = v.x - mean, d1 = v.y - mean, d2 = v.z - mean, d3 = v.w - mean;
    float q = d0 * d0 + d1 * d1 + d2 * d2 + d3 * d3;
#pragma unroll
    for (int o = 32; o; o >>= 1) q += __shfl_xor(q, o);
    const float rs = rsqrtf(q * (1.f / D_) + 1e-12f);
    const float4 gg = ((const float4*)g)[lane];
    const float4 bb = ((const float4*)b)[lane];
    bf16x4 o4 = {(bf16_t)(d0 * rs * gg.x + bb.x), (bf16_t)(d1 * rs * gg.y + bb.y),
                 (bf16_t)(d2 * rs * gg.z + bb.z), (bf16_t)(d3 * rs * gg.w + bb.w)};
    ((bf16x4*)y)[idx] = o4;
  }
}

// embed combine: x = relu(LN(sum4(parts)+bias)); y = LN1(x) bf16
__global__ __launch_bounds__(256) void embed_combine(
    const float* __restrict__ parts, const float* __restrict__ bias,
    const float* __restrict__ g0, const float* __restrict__ b0,
    const float* __restrict__ g1, const float* __restrict__ b1,
    float* __restrict__ x, bf16_t* __restrict__ y) {
  const int row = blockIdx.x * 4 + (threadIdx.x >> 6);
  const int lane = threadIdx.x & 63;
  const size_t idx = (size_t)row * 64 + lane;
  float4 v = ((const float4*)parts)[idx];
#pragma unroll
  for (int p = 1; p < 4; ++p) {
    float4 pv = ((const float4*)parts)[(size_t)p * NROW * 64 + idx];
    v.x += pv.x; v.y += pv.y; v.z += pv.z; v.w += pv.w;
  }
  const float4 bi = ((const float4*)bias)[lane];
  v.x += bi.x; v.y += bi.y; v.z += bi.z; v.w += bi.w;
  float s = v.x + v.y + v.z + v.w;
#pragma unroll
  for (int o = 32; o; o >>= 1) s += __shfl_xor(s, o);
  float mean = s * (1.f / D_);
  float d0 = v.x - mean, d1 = v.y - mean, d2 = v.z - mean, d3 = v.w - mean;
  float q = d0 * d0 + d1 * d1 + d2 * d2 + d3 * d3;
#pragma unroll
  for (int o = 32; o; o >>= 1) q += __shfl_xor(q, o);
  float rs = rsqrtf(q * (1.f / D_) + 1e-12f);
  const float4 gg = ((const float4*)g0)[lane];
  const float4 bb = ((const float4*)b0)[lane];
  float x0 = fmaxf(d0 * rs * gg.x + bb.x, 0.f);
  float x1 = fmaxf(d1 * rs * gg.y + bb.y, 0.f);
  float x2 = fmaxf(d2 * rs * gg.z + bb.z, 0.f);
  float x3 = fmaxf(d3 * rs * gg.w + bb.w, 0.f);
  ((float4*)x)[idx] = make_float4(x0, x1, x2, x3);
  // second LN (ln1 of layer 0)
  s = x0 + x1 + x2 + x3;
#pragma unroll
  for (int o = 32; o; o >>= 1) s += __shfl_xor(s, o);
  mean = s * (1.f / D_);
  d0 = x0 - mean; d1 = x1 - mean; d2 = x2 - mean; d3 = x3 - mean;
  q = d0 * d0 + d1 * d1 + d2 * d2 + d3 * d3;
#pragma unroll
  for (int o = 32; o; o >>= 1) q += __shfl_xor(q, o);
  rs = rsqrtf(q * (1.f / D_) + 1e-12f);
  const float4 g1v = ((const float4*)g1)[lane];
  const float4 b1v = ((const float4*)b1)[lane];
  bf16x4 o4 = {(bf16_t)(d0 * rs * g1v.x + b1v.x), (bf16_t)(d1 * rs * g1v.y + b1v.y),
               (bf16_t)(d2 * rs * g1v.z + b1v.z), (bf16_t)(d3 * rs * g1v.w + b1v.w)};
  ((bf16x4*)y)[idx] = o4;
}

// ---------------------------------------------------------------------------
// bf16 NT GEMM, BK=64: C[M,N] = A[M,K] * B[N,K]^T, split-K via blockIdx.z.
// EP: 1 bf16 bias; 2 bf16 bias+relu; 4 f32 raw partial at Cout + z*zstride
// ---------------------------------------------------------------------------
template <int BM, int BN, int EP, int MINW>
__global__ __launch_bounds__(256, MINW) void gemm_bf16(
    const bf16_t* __restrict__ A, int lda, const bf16_t* __restrict__ B, int ldb,
    const float* __restrict__ bias, void* __restrict__ Cout, int ldc,
    int K, size_t zstride) {
  constexpr int HM = BM / 2, HN = BN / 2;
  constexpr int FM = HM / 16, FN = HN / 16;
  constexpr int CA = (BM * 8) / 256, CB = (BN * 8) / 256;
  __shared__ bf16_t lsA[BM * 64];
  __shared__ bf16_t lsB[BN * 64];
  const int tid = threadIdx.x;
  const int w = tid >> 6, lane = tid & 63;
  const int wm = w >> 1, wn = w & 1;
  const int lanelo = lane & 15, quad = lane >> 4;
  const int wbase = tid & ~63;
  const int m0 = blockIdx.x * BM, n0 = blockIdx.y * BN;
  const int ktiles = K >> 6;
  const int tpz = (ktiles + gridDim.z - 1) / gridDim.z;
  const int kb = blockIdx.z * tpz * 64;
  const int ke = min(K, kb + tpz * 64);
  f32x4 acc[FM][FN] = {};

  for (int kt = kb; kt < ke; kt += 64) {
    __syncthreads();
#pragma unroll
    for (int rr = 0; rr < CA; ++rr) {
      int chunk = rr * 256 + tid;
      int r = chunk >> 3, c8 = chunk & 7;
      int lg = c8 ^ (r & 7);
      async_cp16(A + (size_t)(m0 + r) * lda + kt + lg * 8,
                 lsA + (size_t)(rr * 256 + wbase) * 8);
    }
#pragma unroll
    for (int rr = 0; rr < CB; ++rr) {
      int chunk = rr * 256 + tid;
      int r = chunk >> 3, c8 = chunk & 7;
      int lg = c8 ^ (r & 7);
      async_cp16(B + (size_t)(n0 + r) * ldb + kt + lg * 8,
                 lsB + (size_t)(rr * 256 + wbase) * 8);
    }
    __syncthreads();
    bf16x8 af[FM][2], bfv[FN][2];
#pragma unroll
    for (int i = 0; i < FM; ++i) {
      int r = wm * HM + i * 16 + lanelo;
#pragma unroll
      for (int kk = 0; kk < 2; ++kk)
        af[i][kk] = *(const bf16x8*)(lsA + (size_t)(r * 8 + ((kk * 4 + quad) ^ (r & 7))) * 8);
    }
#pragma unroll
    for (int j = 0; j < FN; ++j) {
      int r = wn * HN + j * 16 + lanelo;
#pragma unroll
      for (int kk = 0; kk < 2; ++kk)
        bfv[j][kk] = *(const bf16x8*)(lsB + (size_t)(r * 8 + ((kk * 4 + quad) ^ (r & 7))) * 8);
    }
#pragma unroll
    for (int kk = 0; kk < 2; ++kk)
#pragma unroll
      for (int i = 0; i < FM; ++i)
#pragma unroll
        for (int j = 0; j < FN; ++j)
          acc[i][j] = mfma16(af[i][kk], bfv[j][kk], acc[i][j]);
  }

#pragma unroll
  for (int i = 0; i < FM; ++i) {
#pragma unroll
    for (int j = 0; j < FN; ++j) {
#pragma unroll
      for (int reg = 0; reg < 4; ++reg) {
        const int m = m0 + wm * HM + i * 16 + quad * 4 + reg;
        const int n = n0 + wn * HN + j * 16 + lanelo;
        const size_t idx = (size_t)m * ldc + n;
        if constexpr (EP == 4) {
          ((float*)Cout + (size_t)blockIdx.z * zstride)[idx] = acc[i][j][reg];
        } else {
          float v = acc[i][j][reg] + bias[n];
          if constexpr (EP == 1) {
            ((bf16_t*)Cout)[idx] = (bf16_t)v;
          } else {
            ((bf16_t*)Cout)[idx] = (bf16_t)fmaxf(v, 0.f);
          }
        }
      }
    }
  }
}

// ---------------------------------------------------------------------------
// Wo GEMM with fused attention-split combine in A staging.
// grid (NROW/64, 256/128, 2): BM=64, BN=128, split-K=2 (K=256; each k-tile
// of 64 is exactly one head). Writes f32 partials to gpart + z*zstride.
// ---------------------------------------------------------------------------
__global__ __launch_bounds__(256, 2) void wo_gemm(
    const bf16_t* __restrict__ Opart, const float* __restrict__ mpart,
    const float* __restrict__ lpart, const bf16_t* __restrict__ B,
    float* __restrict__ Cout, size_t zstride) {
  __shared__ bf16_t lsA[64 * 64];
  __shared__ bf16_t lsB[128 * 64];
  const int tid = threadIdx.x;
  const int w = tid >> 6, lane = tid & 63;
  const int wm = w >> 1, wn = w & 1;
  const int lanelo = lane & 15, quad = lane >> 4;
  const int wbase = tid & ~63;
  const int m0 = blockIdx.x * 64, n0 = blockIdx.y * 128;
  const int z = blockIdx.z;
  const int bb = m0 >> 9, t0 = m0 & 511;
  f32x4 acc[2][4] = {};

  for (int kt = z * 128; kt < z * 128 + 128; kt += 64) {
    __syncthreads();
    // A staging with inline split-combine (one head per k-tile)
    const int hh = kt >> 6;
    const int bh = bb * 4 + hh;
#pragma unroll
    for (int rr = 0; rr < 2; ++rr) {
      int chunk = rr * 256 + tid;
      int r = chunk >> 3, c8 = chunk & 7;
      int dk0 = (c8 ^ (r & 7)) * 8;
      int t = t0 + r;
      float mp[NSA], lp[NSA];
      float mmax = -__builtin_inff();
#pragma unroll
      for (int p = 0; p < NSA; ++p) {
        const size_t prow = ((size_t)p * NBH + bh) * T_ + t;
        mp[p] = mpart[prow]; lp[p] = lpart[prow];
        mmax = fmaxf(mmax, mp[p]);
      }
      float e[NSA], denom = 0.f;
#pragma unroll
      for (int p = 0; p < NSA; ++p) {
        e[p] = __expf(mp[p] - mmax);
        denom += lp[p] * e[p];
      }
      const float inv = (denom > 0.f) ? 1.f / denom : 0.f;
      float cv[8] = {};
#pragma unroll
      for (int p = 0; p < NSA; ++p) {
        const float wgt = e[p] * inv;
        bf16x8 op = *(const bf16x8*)(Opart +
            (((size_t)p * NBH + bh) * T_ + t) * 64 + dk0);
#pragma unroll
        for (int i = 0; i < 8; ++i) cv[i] += wgt * (float)op[i];
      }
      bf16x8 rv;
#pragma unroll
      for (int i = 0; i < 8; ++i) rv[i] = (bf16_t)cv[i];
      *(bf16x8*)(lsA + (size_t)chunk * 8) = rv;
    }
    // B staging (async)
#pragma unroll
    for (int rr = 0; rr < 4; ++rr) {
      int chunk = rr * 256 + tid;
      int r = chunk >> 3, c8 = chunk & 7;
      int lg = c8 ^ (r & 7);
      async_cp16(B + (size_t)(n0 + r) * 256 + kt + lg * 8,
                 lsB + (size_t)(rr * 256 + wbase) * 8);
    }
    __syncthreads();
    bf16x8 af[2][2], bfv[4][2];
#pragma unroll
    for (int i = 0; i < 2; ++i) {
      int r = wm * 32 + i * 16 + lanelo;
#pragma unroll
      for (int kk = 0; kk < 2; ++kk)
        af[i][kk] = *(const bf16x8*)(lsA + (size_t)(r * 8 + ((kk * 4 + quad) ^ (r & 7))) * 8);
    }
#pragma unroll
    for (int j = 0; j < 4; ++j) {
      int r = wn * 64 + j * 16 + lanelo;
#pragma unroll
      for (int kk = 0; kk < 2; ++kk)
        bfv[j][kk] = *(const bf16x8*)(lsB + (size_t)(r * 8 + ((kk * 4 + quad) ^ (r & 7))) * 8);
    }
#pragma unroll
    for (int kk = 0; kk < 2; ++kk)
#pragma unroll
      for (int i = 0; i < 2; ++i)
#pragma unroll
        for (int j = 0; j < 4; ++j)
          acc[i][j] = mfma16(af[i][kk], bfv[j][kk], acc[i][j]);
  }

#pragma unroll
  for (int i = 0; i < 2; ++i)
#pragma unroll
    for (int j = 0; j < 4; ++j)
#pragma unroll
      for (int reg = 0; reg < 4; ++reg) {
        const int m = m0 + wm * 32 + i * 16 + quad * 4 + reg;
        const int n = n0 + wn * 64 + j * 16 + lanelo;
        (Cout + (size_t)z * zstride)[(size_t)m * D_ + n] = acc[i][j][reg];
      }
}

// ---------------------------------------------------------------------------
// Fused flash attention w/ LDS-resident rel-pos bias.
// grid (T/64, NBH, NSA); per block: R GEMM once (192-wide window), then 2
// s-tiles flash. LDS 50.5 KB -> 3 blocks/CU; 2 barriers per s-tile.
// ---------------------------------------------------------------------------
__global__ __launch_bounds__(256, 3) void attn_fused(
    const bf16_t* __restrict__ qkv, const bf16_t* __restrict__ pkn,
    const int* __restrict__ masks, bf16_t* __restrict__ Opart,
    float* __restrict__ mpart, float* __restrict__ lpart) {
  __shared__ bf16_t ls_qp[64 * 72];    // q staged (64x64 swz); later P (LD72)
  __shared__ bf16_t ls_pkr[64 * 196];  // pk staged (192x64 swz); later R (LD196)
  __shared__ bf16_t ls_k[64 * 64];     // swizzled
  __shared__ bf16_t ls_vt[64 * 72];    // [d][s], LD72

  const int tid = threadIdx.x, w = tid >> 6, lane = tid & 63;
  const int lanelo = lane & 15, quad = lane >> 4;
  const int wbase = tid & ~63;
  const int t0 = blockIdx.x * 64;
  const int bh = blockIdx.y, bb = bh >> 2, h = bh & 3;
  const int z = blockIdx.z;
  const size_t rowbase = (size_t)bb * T_;
  const int jb = t0 - 128 * z + 873;  // rel index window base (489..1321)

  // stage q + 192 pkn rows (async)
#pragma unroll
  for (int rr = 0; rr < 2; ++rr) {
    int chunk = rr * 256 + tid;
    int r = chunk >> 3, c8 = chunk & 7;
    int lg = c8 ^ (r & 7);
    async_cp16(qkv + (rowbase + t0 + r) * 768 + h * 64 + lg * 8,
               ls_qp + (size_t)(rr * 256 + wbase) * 8);
  }
#pragma unroll
  for (int rr = 0; rr < 6; ++rr) {
    int chunk = rr * 256 + tid;
    int r = chunk >> 3, c8 = chunk & 7;
    int lg = c8 ^ (r & 7);
    async_cp16(pkn + (size_t)(jb + r) * DK + lg * 8,
               ls_pkr + (size_t)(rr * 256 + wbase) * 8);
  }
  __syncthreads();
  bf16x8 qf[2];
#pragma unroll
  for (int kk = 0; kk < 2; ++kk) {
    int r = w * 16 + lanelo;
    qf[kk] = *(const bf16x8*)(ls_qp + (size_t)(r * 8 + ((kk * 4 + quad) ^ (r & 7))) * 8);
  }
  // R GEMM: R[t][jj] = q[t] . pkn[jb+jj], t in wave-own 16-row band
  f32x4 racc[12] = {};
#pragma unroll
  for (int kk = 0; kk < 2; ++kk)
#pragma unroll
    for (int nf = 0; nf < 12; ++nf) {
      int r = nf * 16 + lanelo;
      bf16x8 bj = *(const bf16x8*)(ls_pkr + (size_t)(r * 8 + ((kk * 4 + quad) ^ (r & 7))) * 8);
      racc[nf] = mfma16(qf[kk], bj, racc[nf]);
    }
  __syncthreads();  // pk reads complete -> reuse ls_pkr as R
#pragma unroll
  for (int nf = 0; nf < 12; ++nf)
#pragma unroll
    for (int reg = 0; reg < 4; ++reg)
      ls_pkr[(w * 16 + quad * 4 + reg) * 196 + nf * 16 + lanelo] =
          (bf16_t)racc[nf][reg];
  // R rows are wave-own: later gathers are same-wave, no barrier needed.

  f32x4 o_acc[4] = {};
  float m_run[4], l_run[4];
#pragma unroll
  for (int i = 0; i < 4; ++i) { m_run[i] = -__builtin_inff(); l_run[i] = 0.f; }

  for (int stl = 0; stl < 2; ++stl) {
    const int s0 = 128 * z + 64 * stl;
    __syncthreads();  // prev-tile k/vt reads complete
    // stage K (async, swizzled)
#pragma unroll
    for (int rr = 0; rr < 2; ++rr) {
      int chunk = rr * 256 + tid;
      int r = chunk >> 3, c8 = chunk & 7;
      int lg = c8 ^ (r & 7);
      async_cp16(qkv + (rowbase + s0 + r) * 768 + 256 + h * 64 + lg * 8,
                 ls_k + (size_t)(rr * 256 + wbase) * 8);
    }
    // stage V^T [d][s] (manual, conflict-free)
#pragma unroll
    for (int c = tid; c < 64 * 8; c += 256) {
      int r = c & 63, d0 = (c >> 6) * 8;
      bf16x8 vv = *(const bf16x8*)(qkv + (rowbase + s0 + r) * 768 + 512 + h * 64 + d0);
#pragma unroll
      for (int i = 0; i < 8; ++i) ls_vt[(d0 + i) * 72 + r] = vv[i];
    }
    // mask tile
    int mk[4];
#pragma unroll
    for (int nf = 0; nf < 4; ++nf)
      mk[nf] = masks[bb * T_ + s0 + nf * 16 + lanelo];
    __syncthreads();

    // S GEMM
    f32x4 sacc[4] = {};
#pragma unroll
    for (int kk = 0; kk < 2; ++kk)
#pragma unroll
      for (int nf = 0; nf < 4; ++nf) {
        int r = nf * 16 + lanelo;
        bf16x8 bk = *(const bf16x8*)(ls_k + (size_t)(r * 8 + ((kk * 4 + quad) ^ (r & 7))) * 8);
        sacc[nf] = mfma16(qf[kk], bk, sacc[nf]);
      }
    // gather rel-bias from LDS R: jj = trow - scol - 64*stl + 127
    float sv[4][4];
#pragma unroll
    for (int nf = 0; nf < 4; ++nf) {
      const int scol = nf * 16 + lanelo;
#pragma unroll
      for (int reg = 0; reg < 4; ++reg) {
        const int trow = w * 16 + quad * 4 + reg;
        const float bt = (float)ls_pkr[trow * 196 + (trow - scol - 64 * stl + 127)];
        sv[nf][reg] = mk[nf] ? (sacc[nf][reg] + bt) * 0.125f : -3.4028235e38f;
      }
    }
    // online softmax
    float alpha[4];
#pragma unroll
    for (int reg = 0; reg < 4; ++reg) {
      float bm = fmaxf(fmaxf(sv[0][reg], sv[1][reg]), fmaxf(sv[2][reg], sv[3][reg]));
#pragma unroll
      for (int o = 1; o < 16; o <<= 1) bm = fmaxf(bm, __shfl_xor(bm, o));
      const float mn = fmaxf(m_run[reg], bm);
      alpha[reg] = __expf(m_run[reg] - mn);
      m_run[reg] = mn;
      float rsum = 0.f;
#pragma unroll
      for (int nf = 0; nf < 4; ++nf) {
        float p = __expf(sv[nf][reg] - mn) * (mk[nf] ? 1.f : 0.f);
        sv[nf][reg] = p;
        rsum += p;
      }
#pragma unroll
      for (int o = 1; o < 16; o <<= 1) rsum += __shfl_xor(rsum, o);
      l_run[reg] = l_run[reg] * alpha[reg] + rsum;
    }
    // P write (wave-own rows of ls_qp, LD72) + PV
#pragma unroll
    for (int nf = 0; nf < 4; ++nf)
#pragma unroll
      for (int reg = 0; reg < 4; ++reg) {
        o_acc[nf][reg] *= alpha[reg];
        ls_qp[(w * 16 + quad * 4 + reg) * 72 + nf * 16 + lanelo] = (bf16_t)sv[nf][reg];
      }
#pragma unroll
    for (int kk = 0; kk < 2; ++kk) {
      bf16x8 ap = *(const bf16x8*)&ls_qp[(w * 16 + lanelo) * 72 + kk * 32 + quad * 8];
#pragma unroll
      for (int nf = 0; nf < 4; ++nf) {
        bf16x8 bv = *(const bf16x8*)&ls_vt[(nf * 16 + lanelo) * 72 + kk * 32 + quad * 8];
        o_acc[nf] = mfma16(ap, bv, o_acc[nf]);
      }
    }
  }

  // write split partials (bf16 O + f32 m,l)
#pragma unroll
  for (int reg = 0; reg < 4; ++reg) {
    const int trow = w * 16 + quad * 4 + reg;
    const size_t prow = ((size_t)z * NBH + bh) * T_ + t0 + trow;
#pragma unroll
    for (int nf = 0; nf < 4; ++nf)
      Opart[prow * 64 + nf * 16 + lanelo] = (bf16_t)o_acc[nf][reg];
    if (lanelo == 0) { mpart[prow] = m_run[reg]; lpart[prow] = l_run[reg]; }
  }
}

// ---------------------------------------------------------------------------
// host
// ---------------------------------------------------------------------------
extern "C" void kernel_launch(void* const* d_in, const int* in_sizes, int n_in,
                              void* d_out, int out_size, void* d_ws, size_t ws_size,
                              hipStream_t stream) {
  const float* xs       = (const float*)d_in[0];
  const int*   masks    = (const int*)d_in[1];
  const float* emb_w    = (const float*)d_in[2];
  const float* emb_b    = (const float*)d_in[3];
  const float* emb_g    = (const float*)d_in[4];
  const float* emb_beta = (const float*)d_in[5];
  const float* pe_k     = (const float*)d_in[6];
  const float* Wq       = (const float*)d_in[7];
  const float* bq       = (const float*)d_in[8];
  const float* Wk       = (const float*)d_in[9];
  const float* bk       = (const float*)d_in[10];
  const float* Wv       = (const float*)d_in[11];
  const float* bv       = (const float*)d_in[12];
  const float* Wo       = (const float*)d_in[13];
  const float* bo       = (const float*)d_in[14];
  const float* ln1_g    = (const float*)d_in[15];
  const float* ln1_b    = (const float*)d_in[16];
  const float* ln2_g    = (const float*)d_in[17];
  const float* ln2_b    = (const float*)d_in[18];
  const float* lnk_g    = (const float*)d_in[19];
  const float* lnk_b    = (const float*)d_in[20];
  const float* W1       = (const float*)d_in[21];
  const float* b1       = (const float*)d_in[22];
  const float* W2       = (const float*)d_in[23];
  const float* b2       = (const float*)d_in[24];
  const float* after_g  = (const float*)d_in[25];
  const float* after_b  = (const float*)d_in[26];

  char* ws = (char*)d_ws;
  size_t off = 0;
  auto take = [&](size_t bytes) -> void* {
    void* p = ws + off;
    off += (bytes + 255) & ~(size_t)255;
    return p;
  };
  bf16_t* ewb  = (bf16_t*)take((size_t)D_ * KPAD * 2);
  bf16_t* wcat = (bf16_t*)take((size_t)L_ * 768 * D_ * 2);
  float*  bcat = (float*) take((size_t)L_ * 768 * 4);
  bf16_t* wob  = (bf16_t*)take((size_t)L_ * D_ * D_ * 2);
  bf16_t* w1b  = (bf16_t*)take((size_t)L_ * FF_ * D_ * 2);
  bf16_t* w2b  = (bf16_t*)take((size_t)L_ * D_ * FF_ * 2);
  bf16_t* pknb = (bf16_t*)take((size_t)L_ * PKROWS * DK * 2);
  float*  x    = (float*) take((size_t)NROW * D_ * 4);
  bf16_t* y    = (bf16_t*)take((size_t)NROW * D_ * 2);
  bf16_t* qkv  = (bf16_t*)take((size_t)NROW * 768 * 2);
  bf16_t* hbuf = (bf16_t*)take((size_t)NROW * FF_ * 2);
  bf16_t* Opart = (bf16_t*)take((size_t)NSA * NBH * T_ * 64 * 2);  // 8.4 MB
  float*  mpart = (float*)take((size_t)NSA * NBH * T_ * 4);
  float*  lpart = (float*)take((size_t)NSA * NBH * T_ * 4);
  float*  gpart = (float*)take((size_t)4 * NROW * D_ * 4);         // 16.8 MB
  bf16_t* xsb  = hbuf;  // xs bf16 (15.2MB) only needed before first FF1
  const size_t ZS = (size_t)NROW * D_;

  // prep (per-call; inputs restored by harness each launch)
  cvt_pad_row<<<NROW, 256, 0, stream>>>(xs, xsb, IDIM, KPAD);
  cvt_pad_row<<<D_, 256, 0, stream>>>(emb_w, ewb, IDIM, KPAD);
  pack_qkvw<<<2048, 256, 0, stream>>>(Wq, Wk, Wv, wcat);
  pack_qkvb<<<48, 256, 0, stream>>>(bq, bk, bv, bcat);
  cvt_f32_bf16<<<1024, 256, 0, stream>>>(Wo, wob, L_ * D_ * D_);
  cvt_f32_bf16<<<2048, 256, 0, stream>>>(W1, w1b, L_ * FF_ * D_);
  cvt_f32_bf16<<<2048, 256, 0, stream>>>(W2, w2b, L_ * D_ * FF_);
  pkn_ln<<<(L_ * PKROWS) / 4, 256, 0, stream>>>(pe_k, lnk_g, lnk_b, pknb);

  // embed: 128x128 split-K=4 -> combine (LN+relu, then ln1 of layer 0)
  gemm_bf16<128, 128, 4, 2><<<dim3(NROW / 128, D_ / 128, 4), 256, 0, stream>>>(
      xsb, KPAD, ewb, KPAD, nullptr, gpart, D_, KPAD, ZS);
  embed_combine<<<NROW / 4, 256, 0, stream>>>(gpart, emb_b, emb_g, emb_beta,
                                              ln1_g, ln1_b, x, y);

  for (int l = 0; l < L_; ++l) {
    // QKV projection
    gemm_bf16<64, 128, 1, 3><<<dim3(NROW / 64, 768 / 128), 256, 0, stream>>>(
        y, D_, wcat + (size_t)l * 768 * D_, D_, bcat + l * 768, qkv, 768, D_, 0);
    // fused flash attention (rel-bias in LDS), s-split 4
    attn_fused<<<dim3(T_ / 64, NBH, NSA), 256, 0, stream>>>(
        qkv, pknb + (size_t)l * PKROWS * DK, masks, Opart, mpart, lpart);
    // Wo GEMM with inline split-combine; split-K=2 partials
    wo_gemm<<<dim3(NROW / 64, D_ / 128, 2), 256, 0, stream>>>(
        Opart, mpart, lpart, wob + (size_t)l * D_ * D_, gpart, ZS);
    add_combine_ln<2, true><<<NROW / 4, 256, 0, stream>>>(
        gpart, bo + l * D_, x, ln2_g + l * D_, ln2_b + l * D_, y);
    // FF1
    gemm_bf16<128, 128, 2, 2><<<dim3(NROW / 128, FF_ / 128), 256, 0, stream>>>(
        y, D_, w1b + (size_t)l * FF_ * D_, D_, b1 + l * FF_, hbuf, FF_, D_, 0);
    // FF2: 128x128 split-K=4
    gemm_bf16<128, 128, 4, 2><<<dim3(NROW / 128, D_ / 128, 4), 256, 0, stream>>>(
        hbuf, FF_, w2b + (size_t)l * D_ * FF_, FF_, nullptr, gpart, D_, FF_, ZS);
    if (l < L_ - 1) {
      add_combine_ln<4, true><<<NROW / 4, 256, 0, stream>>>(
          gpart, b2 + l * D_, x, ln1_g + (l + 1) * D_, ln1_b + (l + 1) * D_, y);
    } else {
      add_combine_ln<4, false><<<NROW / 4, 256, 0, stream>>>(
          gpart, b2 + l * D_, x, nullptr, nullptr, nullptr);
    }
  }
  ln_rows_f32<<<NROW / 4, 256, 0, stream>>>(x, after_g, after_b, (float*)d_out);
}